// Round 1
// baseline (2813.212 us; speedup 1.0000x reference)
//
#include <hip/hip_runtime.h>
#include <hip/hip_bf16.h>
#include <math.h>

#define IMG_H 224
#define P 3
#define FEAT_HW 13
#define C_FEAT 384
#define N_VIS (C_FEAT * P * P)   // 3456
#define HID 300
#define N_CLASSES 4
#define BN_EPS 1e-5f
#define BATCH 8
#define NROI 1024
#define K2 10
#define NTOT (N_VIS + HID + 4)   // 3760

// ---------------- generic direct conv (one thread per output) ----------------
__global__ void conv2d_kernel(const float* __restrict__ in, const float* __restrict__ w,
                              const float* __restrict__ bias, float* __restrict__ out,
                              int Bn, int Cin, int Hin, int Win, int Cout, int Hout, int Wout,
                              int KS, int stride, int pad, int do_relu)
{
    int idx = blockIdx.x * blockDim.x + threadIdx.x;
    int total = Bn * Cout * Hout * Wout;
    if (idx >= total) return;
    int ow = idx % Wout; int t = idx / Wout;
    int oh = t % Hout;   t /= Hout;
    int oc = t % Cout;   int b = t / Cout;

    float acc = bias[oc];
    int ih0 = oh * stride - pad, iw0 = ow * stride - pad;
    const float* wbase = w + (size_t)oc * Cin * KS * KS;
    const float* ibase = in + (size_t)b * Cin * Hin * Win;
    for (int ic = 0; ic < Cin; ++ic) {
        const float* ip = ibase + (size_t)ic * Hin * Win;
        const float* wp = wbase + (size_t)ic * KS * KS;
        for (int kh = 0; kh < KS; ++kh) {
            int ih = ih0 + kh;
            if (ih < 0 || ih >= Hin) continue;
            const float* irow = ip + (size_t)ih * Win;
            const float* wrow = wp + kh * KS;
            for (int kw = 0; kw < KS; ++kw) {
                int iw = iw0 + kw;
                if (iw < 0 || iw >= Win) continue;
                acc += irow[iw] * wrow[kw];
            }
        }
    }
    if (do_relu) acc = fmaxf(acc, 0.f);
    out[idx] = acc;
}

// ---------------- 3x3 stride2 VALID maxpool ----------------
__global__ void maxpool3s2_kernel(const float* __restrict__ in, float* __restrict__ out,
                                  int BC, int Hin, int Win, int Hout, int Wout)
{
    int idx = blockIdx.x * blockDim.x + threadIdx.x;
    int total = BC * Hout * Wout;
    if (idx >= total) return;
    int ow = idx % Wout; int t = idx / Wout;
    int oh = t % Hout;   int bc = t / Hout;
    const float* ip = in + (size_t)bc * Hin * Win;
    int ih0 = oh * 2, iw0 = ow * 2;
    float v = -INFINITY;
    #pragma unroll
    for (int kh = 0; kh < 3; ++kh) {
        const float* row = ip + (size_t)(ih0 + kh) * Win + iw0;
        v = fmaxf(v, fmaxf(fmaxf(row[0], row[1]), row[2]));
    }
    out[idx] = v;
}

// ---------------- ROI max-pool (matches reference bin math exactly) ----------------
__global__ void roi_pool_kernel(const float* __restrict__ feat, const float* __restrict__ bboxes,
                                float* __restrict__ own, int N, int C, int H, int W)
{
    int idx = blockIdx.x * blockDim.x + threadIdx.x;
    if (idx >= N * C) return;
    int n = idx / C, c = idx % C;
    const float* bb = bboxes + (size_t)n * 5;
    int img = (int)bb[0];
    const float SC = 13.0f / 224.0f;
    int x1 = (int)rintf(bb[1] * SC);
    int y1 = (int)rintf(bb[2] * SC);
    int x2 = (int)rintf(bb[3] * SC);
    int y2 = (int)rintf(bb[4] * SC);
    int roi_w = max(x2 - x1 + 1, 1);
    int roi_h = max(y2 - y1 + 1, 1);
    const float* f = feat + ((size_t)img * C + c) * H * W;
    float* o = own + (size_t)n * (C * 9) + (size_t)c * 9;
    for (int ph = 0; ph < 3; ++ph) {
        int hstart = min(max(y1 + (ph * roi_h) / 3, 0), H);
        int hend   = min(max(y1 + ((ph + 1) * roi_h + 2) / 3, 0), H);
        for (int pw = 0; pw < 3; ++pw) {
            int wstart = min(max(x1 + (pw * roi_w) / 3, 0), W);
            int wend   = min(max(x1 + ((pw + 1) * roi_w + 2) / 3, 0), W);
            float v;
            if (hend <= hstart || wend <= wstart) {
                v = 0.f;
            } else {
                v = -INFINITY;
                for (int hh = hstart; hh < hend; ++hh)
                    for (int ww = wstart; ww < wend; ++ww)
                        v = fmaxf(v, f[(size_t)hh * W + ww]);
            }
            o[ph * 3 + pw] = v;
        }
    }
}

__global__ void zero_kernel(float* __restrict__ p, int n)
{
    int i = blockIdx.x * blockDim.x + threadIdx.x;
    if (i < n) p[i] = 0.f;
}

// ---------------- fp32 tiled GEMM: C = A(MxK) @ B(KxN), fused epilogue ----------------
// mode 0: C = acc + bias
// mode 1: C = relu( (acc + bias - mean) * g/sqrt(var+eps) + beta )
#define BM 64
#define BN 64
#define BK 16
__global__ __launch_bounds__(256) void gemm_fp32(
    const float* __restrict__ A, const float* __restrict__ B, float* __restrict__ C,
    int M, int N, int K,
    const float* __restrict__ bias,
    const float* __restrict__ g, const float* __restrict__ be,
    const float* __restrict__ mean, const float* __restrict__ var,
    int mode)
{
    __shared__ float As[BK][BM + 1];
    __shared__ float Bs[BK][BN];
    int bm = blockIdx.y * BM, bn = blockIdx.x * BN;
    int tid = threadIdx.x;
    int tx = tid & 15, ty = tid >> 4;
    float acc[4][4] = {};

    for (int k0 = 0; k0 < K; k0 += BK) {
        // A tile: thread loads 4 consecutive k of one m
        {
            int m = tid >> 2, kk = (tid & 3) * 4;
            int gm = bm + m;
            #pragma unroll
            for (int j = 0; j < 4; ++j) {
                int gk = k0 + kk + j;
                As[kk + j][m] = (gm < M && gk < K) ? A[(size_t)gm * K + gk] : 0.f;
            }
        }
        // B tile: thread loads 4 consecutive n of one k
        {
            int kk = tid >> 4, n4 = (tid & 15) * 4;
            int gk = k0 + kk;
            #pragma unroll
            for (int j = 0; j < 4; ++j) {
                int gn = bn + n4 + j;
                Bs[kk][n4 + j] = (gk < K && gn < N) ? B[(size_t)gk * N + gn] : 0.f;
            }
        }
        __syncthreads();
        #pragma unroll
        for (int kk = 0; kk < BK; ++kk) {
            float a[4], b[4];
            #pragma unroll
            for (int i = 0; i < 4; ++i) a[i] = As[kk][ty * 4 + i];
            #pragma unroll
            for (int j = 0; j < 4; ++j) b[j] = Bs[kk][tx * 4 + j];
            #pragma unroll
            for (int i = 0; i < 4; ++i)
                #pragma unroll
                for (int j = 0; j < 4; ++j)
                    acc[i][j] += a[i] * b[j];
        }
        __syncthreads();
    }

    #pragma unroll
    for (int i = 0; i < 4; ++i) {
        int gm = bm + ty * 4 + i;
        if (gm >= M) continue;
        #pragma unroll
        for (int j = 0; j < 4; ++j) {
            int gn = bn + tx * 4 + j;
            if (gn >= N) continue;
            float v = acc[i][j] + bias[gn];
            if (mode == 1) {
                float s = g[gn] / sqrtf(var[gn] + BN_EPS);
                v = (v - mean[gn]) * s + be[gn];
                v = fmaxf(v, 0.f);
            }
            C[(size_t)gm * N + gn] = v;
        }
    }
}

// ---------------- per-row attention projections ----------------
// s_own[r] = enc_all[r] . att_w[0:H)   (only r < Nroi)
// proj_hi[r] = enc_all[r] . att_w[H:2H)
__global__ __launch_bounds__(128) void proj_kernel(
    const float* __restrict__ enc_all, const float* __restrict__ att_w,
    float* __restrict__ s_own, float* __restrict__ proj_hi, int R, int H, int Nroi)
{
    int r = blockIdx.x, tid = threadIdx.x;
    const float* row = enc_all + (size_t)r * H;
    float plo = 0.f, phi = 0.f;
    for (int hh = tid; hh < H; hh += 128) {
        float v = row[hh];
        plo += v * att_w[hh];
        phi += v * att_w[H + hh];
    }
    __shared__ float slo[128], shi[128];
    slo[tid] = plo; shi[tid] = phi;
    __syncthreads();
    for (int s = 64; s > 0; s >>= 1) {
        if (tid < s) { slo[tid] += slo[tid + s]; shi[tid] += shi[tid + s]; }
        __syncthreads();
    }
    if (tid == 0) {
        if (r < Nroi) s_own[r] = slo[0];
        proj_hi[r] = shi[0];
    }
}

// ---------------- attention softmax + ctx_rep + assemble combined row ----------------
__global__ __launch_bounds__(512) void att_combine_kernel(
    const float* __restrict__ enc_all, const int* __restrict__ ci,
    const float* __restrict__ s_own, const float* __restrict__ proj_hi,
    const float* __restrict__ att_b, const float* __restrict__ own,
    const float* __restrict__ bboxes, float* __restrict__ combined,
    int N, int H)
{
    int n = blockIdx.x, tid = threadIdx.x;
    __shared__ float wts[K2];
    __shared__ int rows[K2];
    if (tid < K2) {
        int idx = ci[(size_t)n * K2 + tid];
        int row = (idx < 0) ? N : idx;   // python padded[-1] == zero row (index N)
        rows[tid] = row;
        wts[tid] = s_own[n] + proj_hi[row] + att_b[0];
    }
    __syncthreads();
    if (tid == 0) {
        float mx = wts[0];
        #pragma unroll
        for (int k = 1; k < K2; ++k) mx = fmaxf(mx, wts[k]);
        float sum = 0.f;
        float e[K2];
        #pragma unroll
        for (int k = 0; k < K2; ++k) { e[k] = expf(wts[k] - mx); sum += e[k]; }
        float inv = 1.f / sum;
        #pragma unroll
        for (int k = 0; k < K2; ++k) wts[k] = e[k] * inv;
    }
    __syncthreads();

    float* crow = combined + (size_t)n * NTOT;
    if (tid < H) {
        float acc = 0.f;
        #pragma unroll
        for (int k = 0; k < K2; ++k)
            acc += wts[k] * enc_all[(size_t)rows[k] * H + tid];
        crow[N_VIS + tid] = acc;
    }
    // copy own features
    const float* orow = own + (size_t)n * N_VIS;
    for (int j = tid; j < N_VIS; j += 512) crow[j] = orow[j];
    // xywh
    if (tid >= 508) {
        int j = tid - 508;
        float x1 = bboxes[(size_t)n * 5 + 1];
        float y1 = bboxes[(size_t)n * 5 + 2];
        float x2 = bboxes[(size_t)n * 5 + 3];
        float y2 = bboxes[(size_t)n * 5 + 4];
        float vals[4] = { x1, y1, x2 - x1, y2 - y1 };
        crow[N_VIS + HID + j] = vals[j];
    }
}

// ---------------- final tiny GEMM: out(1024,4) = h(1024,K) @ w2(K,4) + b2 ----------------
__global__ __launch_bounds__(256) void gemv4_kernel(
    const float* __restrict__ h, const float* __restrict__ w2,
    const float* __restrict__ b2, float* __restrict__ out, int K)
{
    int m = blockIdx.x, tid = threadIdx.x;
    const float* hr = h + (size_t)m * K;
    float a0 = 0.f, a1 = 0.f, a2 = 0.f, a3 = 0.f;
    for (int k = tid; k < K; k += 256) {
        float x = hr[k];
        const float* wr = w2 + (size_t)k * 4;
        a0 += x * wr[0]; a1 += x * wr[1]; a2 += x * wr[2]; a3 += x * wr[3];
    }
    __shared__ float red[256][4];
    red[tid][0] = a0; red[tid][1] = a1; red[tid][2] = a2; red[tid][3] = a3;
    __syncthreads();
    for (int s = 128; s > 0; s >>= 1) {
        if (tid < s) {
            #pragma unroll
            for (int j = 0; j < 4; ++j) red[tid][j] += red[tid + s][j];
        }
        __syncthreads();
    }
    if (tid < 4) out[(size_t)m * 4 + tid] = red[0][tid] + b2[tid];
}

extern "C" void kernel_launch(void* const* d_in, const int* in_sizes, int n_in,
                              void* d_out, int out_size, void* d_ws, size_t ws_size,
                              hipStream_t stream)
{
    const float* images = (const float*)d_in[0];
    const float* bboxes = (const float*)d_in[1];
    const int*   ci     = (const int*)  d_in[2];
    const float* c1w = (const float*)d_in[3];
    const float* c1b = (const float*)d_in[4];
    const float* c2w = (const float*)d_in[5];
    const float* c2b = (const float*)d_in[6];
    const float* c3w = (const float*)d_in[7];
    const float* c3b = (const float*)d_in[8];
    const float* enc_w1 = (const float*)d_in[9];
    const float* enc_b1 = (const float*)d_in[10];
    const float* enc_g  = (const float*)d_in[11];
    const float* enc_be = (const float*)d_in[12];
    const float* enc_m  = (const float*)d_in[13];
    const float* enc_v  = (const float*)d_in[14];
    const float* enc_w2 = (const float*)d_in[15];
    const float* enc_b2 = (const float*)d_in[16];
    const float* att_w  = (const float*)d_in[17];
    const float* att_b  = (const float*)d_in[18];
    const float* dec_w1 = (const float*)d_in[19];
    const float* dec_b1 = (const float*)d_in[20];
    const float* dec_g  = (const float*)d_in[21];
    const float* dec_be = (const float*)d_in[22];
    const float* dec_m  = (const float*)d_in[23];
    const float* dec_v  = (const float*)d_in[24];
    const float* dec_w2 = (const float*)d_in[25];
    const float* dec_b2 = (const float*)d_in[26];
    float* out = (float*)d_out;

    float* ws = (float*)d_ws;
    size_t off = 0;
    auto alloc = [&](size_t n) { float* p = ws + off; off += (n + 255) & ~(size_t)255; return p; };

    float* own      = alloc((size_t)(NROI + 1) * N_VIS);   // padded rows [own; 0]
    float* feat     = alloc((size_t)BATCH * C_FEAT * 13 * 13);
    float* mid      = alloc((size_t)(NROI + 1) * HID);
    float* enc_all  = alloc((size_t)(NROI + 1) * HID);
    float* s_own    = alloc(NROI);
    float* proj_hi  = alloc(NROI + 1);
    float* combined = alloc((size_t)NROI * NTOT);
    float* hbuf     = alloc((size_t)NROI * NTOT);

    // conv temporaries alias the `combined` region (dead before stage D)
    float* conv1o = combined;                                  // 8*64*55*55 = 1,548,800
    float* pool1  = conv1o + (size_t)BATCH * 64 * 55 * 55;     // 8*64*27*27 =   373,248
    float* conv2o = pool1  + (size_t)BATCH * 64 * 27 * 27;     // 8*192*27*27 = 1,119,744
    float* pool2  = conv2o + (size_t)BATCH * 192 * 27 * 27;    // 8*192*13*13 =   259,584
    // sum = 3,301,376 < NROI*NTOT = 3,850,240  -> fits inside `combined`

    // ---- stage A: conv feature extractor ----
    {
        int total = BATCH * 64 * 55 * 55;
        conv2d_kernel<<<(total + 255) / 256, 256, 0, stream>>>(
            images, c1w, c1b, conv1o, BATCH, 3, 224, 224, 64, 55, 55, 11, 4, 2, 1);
    }
    {
        int total = BATCH * 64 * 27 * 27;
        maxpool3s2_kernel<<<(total + 255) / 256, 256, 0, stream>>>(
            conv1o, pool1, BATCH * 64, 55, 55, 27, 27);
    }
    {
        int total = BATCH * 192 * 27 * 27;
        conv2d_kernel<<<(total + 255) / 256, 256, 0, stream>>>(
            pool1, c2w, c2b, conv2o, BATCH, 64, 27, 27, 192, 27, 27, 5, 1, 2, 1);
    }
    {
        int total = BATCH * 192 * 13 * 13;
        maxpool3s2_kernel<<<(total + 255) / 256, 256, 0, stream>>>(
            conv2o, pool2, BATCH * 192, 27, 27, 13, 13);
    }
    {
        int total = BATCH * C_FEAT * 13 * 13;
        conv2d_kernel<<<(total + 255) / 256, 256, 0, stream>>>(
            pool2, c3w, c3b, feat, BATCH, 192, 13, 13, C_FEAT, 13, 13, 3, 1, 1, 0);
    }

    // ---- stage B: ROI pool into own; zero the padding row ----
    {
        int total = NROI * C_FEAT;
        roi_pool_kernel<<<(total + 255) / 256, 256, 0, stream>>>(
            feat, bboxes, own, NROI, C_FEAT, 13, 13);
        zero_kernel<<<(N_VIS + 255) / 256, 256, 0, stream>>>(own + (size_t)NROI * N_VIS, N_VIS);
    }

    // ---- stage C: encoder on padded (1025 rows) ----
    {
        dim3 grid((HID + BN - 1) / BN, (NROI + 1 + BM - 1) / BM);
        gemm_fp32<<<grid, 256, 0, stream>>>(own, enc_w1, mid, NROI + 1, HID, N_VIS,
                                            enc_b1, enc_g, enc_be, enc_m, enc_v, 1);
        gemm_fp32<<<grid, 256, 0, stream>>>(mid, enc_w2, enc_all, NROI + 1, HID, HID,
                                            enc_b2, nullptr, nullptr, nullptr, nullptr, 0);
    }

    // ---- stage D: attention ----
    proj_kernel<<<NROI + 1, 128, 0, stream>>>(enc_all, att_w, s_own, proj_hi, NROI + 1, HID, NROI);
    att_combine_kernel<<<NROI, 512, 0, stream>>>(enc_all, ci, s_own, proj_hi, att_b,
                                                 own, bboxes, combined, NROI, HID);

    // ---- stage E: decoder ----
    {
        dim3 grid((NTOT + BN - 1) / BN, (NROI + BM - 1) / BM);
        gemm_fp32<<<grid, 256, 0, stream>>>(combined, dec_w1, hbuf, NROI, NTOT, NTOT,
                                            dec_b1, dec_g, dec_be, dec_m, dec_v, 1);
    }
    gemv4_kernel<<<NROI, 256, 0, stream>>>(hbuf, dec_w2, dec_b2, out, NTOT);
}

// Round 2
// 2006.790 us; speedup vs baseline: 1.4018x; 1.4018x over previous
//
#include <hip/hip_runtime.h>
#include <hip/hip_bf16.h>
#include <math.h>

#define IMG_H 224
#define C_FEAT 384
#define N_VIS (C_FEAT * 9)       // 3456
#define HID 300
#define BN_EPS 1e-5f
#define BATCH 8
#define NROI 1024
#define K2 10
#define NTOT (N_VIS + HID + 4)   // 3760

// ================= weight transpose: wt[k][oc] = w[oc][ic][kh][kw], k=(kh*KS+kw)*Cin+ic =====
__global__ void wtrans_kernel(const float* __restrict__ w, float* __restrict__ wt,
                              int Cout, int Cin, int KS)
{
    int K = Cin * KS * KS;
    int idx = blockIdx.x * blockDim.x + threadIdx.x;
    if (idx >= Cout * K) return;
    int oc = idx / K, k = idx % K;
    int ic = k % Cin, q = k / Cin;
    int kw = q % KS, kh = q / KS;
    wt[(size_t)k * Cout + oc] = w[((size_t)oc * Cin + ic) * KS * KS + kh * KS + kw];
}

// ================= im2col kernels =================
// conv1: images NCHW [8][3][224][224], stride4 pad2, out 55x55. k=(kh*11+kw)*3+ic (363)
__global__ void im2col_conv1(const float* __restrict__ img, float* __restrict__ col,
                             int b0, int nb)
{
    int idx = blockIdx.x * blockDim.x + threadIdx.x;
    int total = nb * 3025 * 363;
    if (idx >= total) return;
    int k = idx % 363, r = idx / 363;
    int ow = r % 55, t = r / 55;
    int oh = t % 55, bi = t / 55;
    int ic = k % 3, q = k / 3;
    int kw = q % 11, kh = q / 11;
    int ih = oh * 4 - 2 + kh, iw = ow * 4 - 2 + kw;
    float v = 0.f;
    if (ih >= 0 && ih < 224 && iw >= 0 && iw < 224)
        v = img[(((size_t)(b0 + bi) * 3 + ic) * 224 + ih) * 224 + iw];
    col[idx] = v;
}

// conv2: in pool1 NHWC [8][27][27][64], pad2, k=(kh*5+kw)*64+ic (1600)
__global__ void im2col_conv2(const float* __restrict__ in, float* __restrict__ col,
                             int b0, int nb)
{
    int idx = blockIdx.x * blockDim.x + threadIdx.x;
    int total = nb * 729 * 1600;
    if (idx >= total) return;
    int k = idx % 1600, r = idx / 1600;
    int ow = r % 27, t = r / 27;
    int oh = t % 27, bi = t / 27;
    int ic = k & 63, q = k >> 6;
    int kw = q % 5, kh = q / 5;
    int ih = oh - 2 + kh, iw = ow - 2 + kw;
    float v = 0.f;
    if (ih >= 0 && ih < 27 && iw >= 0 && iw < 27)
        v = in[(((size_t)(b0 + bi) * 27 + ih) * 27 + iw) * 64 + ic];
    col[idx] = v;
}

// conv3: in pool2 NHWC [8][13][13][192], pad1, k=(kh*3+kw)*192+ic (1728)
__global__ void im2col_conv3(const float* __restrict__ in, float* __restrict__ col)
{
    int idx = blockIdx.x * blockDim.x + threadIdx.x;
    int total = 8 * 169 * 1728;
    if (idx >= total) return;
    int k = idx % 1728, r = idx / 1728;
    int ow = r % 13, t = r / 13;
    int oh = t % 13, bi = t / 13;
    int ic = k % 192, q = k / 192;
    int kw = q % 3, kh = q / 3;
    int ih = oh - 1 + kh, iw = ow - 1 + kw;
    float v = 0.f;
    if (ih >= 0 && ih < 13 && iw >= 0 && iw < 13)
        v = in[(((size_t)bi * 13 + ih) * 13 + iw) * 192 + ic];
    col[idx] = v;
}

// ================= NHWC 3x3 stride2 VALID maxpool =================
__global__ void maxpool3s2_nhwc(const float* __restrict__ in, float* __restrict__ out,
                                int Bn, int C, int Hin, int Win, int Hout, int Wout)
{
    int idx = blockIdx.x * blockDim.x + threadIdx.x;
    int total = Bn * Hout * Wout * C;
    if (idx >= total) return;
    int c = idx % C, t = idx / C;
    int ow = t % Wout; t /= Wout;
    int oh = t % Hout; int b = t / Hout;
    const float* base = in + (((size_t)b * Hin + oh * 2) * Win + ow * 2) * C + c;
    float v = -INFINITY;
    #pragma unroll
    for (int kh = 0; kh < 3; ++kh)
        #pragma unroll
        for (int kw = 0; kw < 3; ++kw)
            v = fmaxf(v, base[((size_t)kh * Win + kw) * C]);
    out[idx] = v;
}

// ================= ROI max-pool, NHWC feat =================
__global__ void roi_pool_kernel(const float* __restrict__ feat, const float* __restrict__ bboxes,
                                float* __restrict__ own, int N, int C, int H, int W)
{
    int idx = blockIdx.x * blockDim.x + threadIdx.x;
    if (idx >= N * C) return;
    int n = idx / C, c = idx % C;
    const float* bb = bboxes + (size_t)n * 5;
    int img = (int)bb[0];
    const float SC = 13.0f / 224.0f;
    int x1 = (int)rintf(bb[1] * SC);
    int y1 = (int)rintf(bb[2] * SC);
    int x2 = (int)rintf(bb[3] * SC);
    int y2 = (int)rintf(bb[4] * SC);
    int roi_w = max(x2 - x1 + 1, 1);
    int roi_h = max(y2 - y1 + 1, 1);
    const float* f = feat + (size_t)img * H * W * C + c;
    float* o = own + (size_t)n * (C * 9) + (size_t)c * 9;
    for (int ph = 0; ph < 3; ++ph) {
        int hstart = min(max(y1 + (ph * roi_h) / 3, 0), H);
        int hend   = min(max(y1 + ((ph + 1) * roi_h + 2) / 3, 0), H);
        for (int pw = 0; pw < 3; ++pw) {
            int wstart = min(max(x1 + (pw * roi_w) / 3, 0), W);
            int wend   = min(max(x1 + ((pw + 1) * roi_w + 2) / 3, 0), W);
            float v;
            if (hend <= hstart || wend <= wstart) {
                v = 0.f;
            } else {
                v = -INFINITY;
                for (int hh = hstart; hh < hend; ++hh)
                    for (int ww = wstart; ww < wend; ++ww)
                        v = fmaxf(v, f[((size_t)hh * W + ww) * C]);
            }
            o[ph * 3 + pw] = v;
        }
    }
}

__global__ void zero_kernel(float* __restrict__ p, int n)
{
    int i = blockIdx.x * blockDim.x + threadIdx.x;
    if (i < n) p[i] = 0.f;
}

// ================= fp32 tiled GEMM, C = A(MxK) @ B(KxN), fused epilogue =================
// mode 0: +bias ; mode 1: bias+BN+relu ; mode 2: bias+relu
#define BM 64
#define BK 16
template<int BN_>
__global__ __launch_bounds__(256) void gemm_fp32_t(
    const float* __restrict__ A, const float* __restrict__ B, float* __restrict__ C,
    int M, int N, int K,
    const float* __restrict__ bias,
    const float* __restrict__ g, const float* __restrict__ be,
    const float* __restrict__ mean, const float* __restrict__ var,
    int mode)
{
    constexpr int TN = BN_ / 16;   // 4 (BN=64) or 8 (BN=128)
    __shared__ float As[BK][BM];
    __shared__ float Bs[BK][BN_];
    int bm = blockIdx.y * BM, bn = blockIdx.x * BN_;
    int tid = threadIdx.x;
    int tx = tid & 15, ty = tid >> 4;
    float acc[4][TN];
    #pragma unroll
    for (int i = 0; i < 4; ++i)
        #pragma unroll
        for (int j = 0; j < TN; ++j) acc[i][j] = 0.f;

    for (int k0 = 0; k0 < K; k0 += BK) {
        // A tile: thread loads 4 consecutive k of one m
        {
            int m = tid >> 2, kk = (tid & 3) * 4;
            int gm = bm + m;
            #pragma unroll
            for (int j = 0; j < 4; ++j) {
                int gk = k0 + kk + j;
                As[kk + j][m] = (gm < M && gk < K) ? A[(size_t)gm * K + gk] : 0.f;
            }
        }
        // B tile: thread loads TN consecutive n of one k
        {
            int kk = tid >> 4, nb = (tid & 15) * TN;
            int gk = k0 + kk;
            #pragma unroll
            for (int j = 0; j < TN; ++j) {
                int gn = bn + nb + j;
                Bs[kk][nb + j] = (gk < K && gn < N) ? B[(size_t)gk * N + gn] : 0.f;
            }
        }
        __syncthreads();
        #pragma unroll
        for (int kk = 0; kk < BK; ++kk) {
            float a[4], b[TN];
            #pragma unroll
            for (int i = 0; i < 4; ++i) a[i] = As[kk][ty * 4 + i];
            #pragma unroll
            for (int j = 0; j < TN; ++j) b[j] = Bs[kk][(j >> 2) * 64 + tx * 4 + (j & 3)];
            #pragma unroll
            for (int i = 0; i < 4; ++i)
                #pragma unroll
                for (int j = 0; j < TN; ++j)
                    acc[i][j] += a[i] * b[j];
        }
        __syncthreads();
    }

    #pragma unroll
    for (int i = 0; i < 4; ++i) {
        int gm = bm + ty * 4 + i;
        if (gm >= M) continue;
        #pragma unroll
        for (int j = 0; j < TN; ++j) {
            int gn = bn + (j >> 2) * 64 + tx * 4 + (j & 3);
            if (gn >= N) continue;
            float v = acc[i][j] + bias[gn];
            if (mode == 1) {
                float s = g[gn] / sqrtf(var[gn] + BN_EPS);
                v = (v - mean[gn]) * s + be[gn];
                v = fmaxf(v, 0.f);
            } else if (mode == 2) {
                v = fmaxf(v, 0.f);
            }
            C[(size_t)gm * N + gn] = v;
        }
    }
}

// ================= attention projections =================
__global__ __launch_bounds__(128) void proj_kernel(
    const float* __restrict__ enc_all, const float* __restrict__ att_w,
    float* __restrict__ s_own, float* __restrict__ proj_hi, int R, int H, int Nroi)
{
    int r = blockIdx.x, tid = threadIdx.x;
    const float* row = enc_all + (size_t)r * H;
    float plo = 0.f, phi = 0.f;
    for (int hh = tid; hh < H; hh += 128) {
        float v = row[hh];
        plo += v * att_w[hh];
        phi += v * att_w[H + hh];
    }
    __shared__ float slo[128], shi[128];
    slo[tid] = plo; shi[tid] = phi;
    __syncthreads();
    for (int s = 64; s > 0; s >>= 1) {
        if (tid < s) { slo[tid] += slo[tid + s]; shi[tid] += shi[tid + s]; }
        __syncthreads();
    }
    if (tid == 0) {
        if (r < Nroi) s_own[r] = slo[0];
        proj_hi[r] = shi[0];
    }
}

// ================= attention softmax + ctx_rep + assemble combined row =================
__global__ __launch_bounds__(512) void att_combine_kernel(
    const float* __restrict__ enc_all, const int* __restrict__ ci,
    const float* __restrict__ s_own, const float* __restrict__ proj_hi,
    const float* __restrict__ att_b, const float* __restrict__ own,
    const float* __restrict__ bboxes, float* __restrict__ combined,
    int N, int H)
{
    int n = blockIdx.x, tid = threadIdx.x;
    __shared__ float wts[K2];
    __shared__ int rows[K2];
    if (tid < K2) {
        int idx = ci[(size_t)n * K2 + tid];
        int row = (idx < 0) ? N : idx;
        rows[tid] = row;
        wts[tid] = s_own[n] + proj_hi[row] + att_b[0];
    }
    __syncthreads();
    if (tid == 0) {
        float mx = wts[0];
        #pragma unroll
        for (int k = 1; k < K2; ++k) mx = fmaxf(mx, wts[k]);
        float sum = 0.f;
        float e[K2];
        #pragma unroll
        for (int k = 0; k < K2; ++k) { e[k] = expf(wts[k] - mx); sum += e[k]; }
        float inv = 1.f / sum;
        #pragma unroll
        for (int k = 0; k < K2; ++k) wts[k] = e[k] * inv;
    }
    __syncthreads();

    float* crow = combined + (size_t)n * NTOT;
    if (tid < H) {
        float acc = 0.f;
        #pragma unroll
        for (int k = 0; k < K2; ++k)
            acc += wts[k] * enc_all[(size_t)rows[k] * H + tid];
        crow[N_VIS + tid] = acc;
    }
    const float* orow = own + (size_t)n * N_VIS;
    for (int j = tid; j < N_VIS; j += 512) crow[j] = orow[j];
    if (tid >= 508) {
        int j = tid - 508;
        float x1 = bboxes[(size_t)n * 5 + 1];
        float y1 = bboxes[(size_t)n * 5 + 2];
        float x2 = bboxes[(size_t)n * 5 + 3];
        float y2 = bboxes[(size_t)n * 5 + 4];
        float vals[4] = { x1, y1, x2 - x1, y2 - y1 };
        crow[N_VIS + HID + j] = vals[j];
    }
}

// ================= out(1024,4) = h @ w2 + b2 =================
__global__ __launch_bounds__(256) void gemv4_kernel(
    const float* __restrict__ h, const float* __restrict__ w2,
    const float* __restrict__ b2, float* __restrict__ out, int K)
{
    int m = blockIdx.x, tid = threadIdx.x;
    const float* hr = h + (size_t)m * K;
    float a0 = 0.f, a1 = 0.f, a2 = 0.f, a3 = 0.f;
    for (int k = tid; k < K; k += 256) {
        float x = hr[k];
        const float* wr = w2 + (size_t)k * 4;
        a0 += x * wr[0]; a1 += x * wr[1]; a2 += x * wr[2]; a3 += x * wr[3];
    }
    __shared__ float red[256][4];
    red[tid][0] = a0; red[tid][1] = a1; red[tid][2] = a2; red[tid][3] = a3;
    __syncthreads();
    for (int s = 128; s > 0; s >>= 1) {
        if (tid < s) {
            #pragma unroll
            for (int j = 0; j < 4; ++j) red[tid][j] += red[tid + s][j];
        }
        __syncthreads();
    }
    if (tid < 4) out[(size_t)m * 4 + tid] = red[0][tid] + b2[tid];
}

extern "C" void kernel_launch(void* const* d_in, const int* in_sizes, int n_in,
                              void* d_out, int out_size, void* d_ws, size_t ws_size,
                              hipStream_t stream)
{
    const float* images = (const float*)d_in[0];
    const float* bboxes = (const float*)d_in[1];
    const int*   ci     = (const int*)  d_in[2];
    const float* c1w = (const float*)d_in[3];
    const float* c1b = (const float*)d_in[4];
    const float* c2w = (const float*)d_in[5];
    const float* c2b = (const float*)d_in[6];
    const float* c3w = (const float*)d_in[7];
    const float* c3b = (const float*)d_in[8];
    const float* enc_w1 = (const float*)d_in[9];
    const float* enc_b1 = (const float*)d_in[10];
    const float* enc_g  = (const float*)d_in[11];
    const float* enc_be = (const float*)d_in[12];
    const float* enc_m  = (const float*)d_in[13];
    const float* enc_v  = (const float*)d_in[14];
    const float* enc_w2 = (const float*)d_in[15];
    const float* enc_b2 = (const float*)d_in[16];
    const float* att_w  = (const float*)d_in[17];
    const float* att_b  = (const float*)d_in[18];
    const float* dec_w1 = (const float*)d_in[19];
    const float* dec_b1 = (const float*)d_in[20];
    const float* dec_g  = (const float*)d_in[21];
    const float* dec_be = (const float*)d_in[22];
    const float* dec_m  = (const float*)d_in[23];
    const float* dec_v  = (const float*)d_in[24];
    const float* dec_w2 = (const float*)d_in[25];
    const float* dec_b2 = (const float*)d_in[26];
    float* out = (float*)d_out;

    float* ws = (float*)d_ws;
    size_t off = 0;
    auto alloc = [&](size_t n) { float* p = ws + off; off += (n + 255) & ~(size_t)255; return p; };

    float* own      = alloc((size_t)(NROI + 1) * N_VIS);     // 3,542,400 (padded rows [own;0])
    float* featN    = alloc((size_t)BATCH * 13 * 13 * C_FEAT); // 519,168 (NHWC)
    float* mid      = alloc((size_t)(NROI + 1) * HID);
    float* enc_all  = alloc((size_t)(NROI + 1) * HID);
    float* s_own    = alloc(NROI);
    float* proj_hi  = alloc(NROI + 1);
    float* combined = alloc((size_t)NROI * NTOT);            // 3,850,240
    float* hbuf     = alloc((size_t)NROI * NTOT);            // 3,850,240

    // ---- conv scratch aliases the combined+hbuf span (7,700,480 floats, dead until stage D) ----
    float* H = combined;
    float* wt1 = H;                 //   23,232  (363 x 64)
    float* wt2 = H + 24064;         //  307,200  (1600 x 192)
    float* wt3 = H + 331520;        //  663,552  (1728 x 384)
    float* Pp  = H + 1000192;       // phase area (6,700,288 floats avail)
    float* conv1o = Pp;             // 1,548,800 NHWC 8x55x55x64
    float* col1   = Pp + 1548800;   // 4,392,300 per 4-image chunk
    float* pool1  = Pp + 1548800;   //   373,248 NHWC 8x27x27x64 (after col1 dead)
    float* conv2o = Pp;             // 1,119,744 NHWC 8x27x27x192 (after conv1o dead)
    float* col2   = Pp + 1922048;   // 4,665,600 per 4-image chunk
    float* pool2  = Pp + 1119744;   //   259,584 NHWC 8x13x13x192
    float* col3   = Pp + 1379328;   // 2,336,256

    // ---- weight transposes ----
    wtrans_kernel<<<(64 * 363 + 255) / 256, 256, 0, stream>>>(c1w, wt1, 64, 3, 11);
    wtrans_kernel<<<(192 * 1600 + 255) / 256, 256, 0, stream>>>(c2w, wt2, 192, 64, 5);
    wtrans_kernel<<<(384 * 1728 + 255) / 256, 256, 0, stream>>>(c3w, wt3, 384, 192, 3);

    // ---- conv1: 2 chunks of 4 images ----
    for (int ch = 0; ch < 2; ++ch) {
        int b0 = ch * 4, nb = 4;
        int total = nb * 3025 * 363;
        im2col_conv1<<<(total + 255) / 256, 256, 0, stream>>>(images, col1, b0, nb);
        dim3 grid(1, (nb * 3025 + BM - 1) / BM);
        gemm_fp32_t<64><<<grid, 256, 0, stream>>>(
            col1, wt1, conv1o + (size_t)b0 * 3025 * 64, nb * 3025, 64, 363,
            c1b, nullptr, nullptr, nullptr, nullptr, 2);
    }
    {
        int total = BATCH * 27 * 27 * 64;
        maxpool3s2_nhwc<<<(total + 255) / 256, 256, 0, stream>>>(conv1o, pool1, BATCH, 64, 55, 55, 27, 27);
    }

    // ---- conv2: 2 chunks of 4 images ----
    for (int ch = 0; ch < 2; ++ch) {
        int b0 = ch * 4, nb = 4;
        int total = nb * 729 * 1600;
        im2col_conv2<<<(total + 255) / 256, 256, 0, stream>>>(pool1, col2, b0, nb);
        dim3 grid(3, (nb * 729 + BM - 1) / BM);
        gemm_fp32_t<64><<<grid, 256, 0, stream>>>(
            col2, wt2, conv2o + (size_t)b0 * 729 * 192, nb * 729, 192, 1600,
            c2b, nullptr, nullptr, nullptr, nullptr, 2);
    }
    {
        int total = BATCH * 13 * 13 * 192;
        maxpool3s2_nhwc<<<(total + 255) / 256, 256, 0, stream>>>(conv2o, pool2, BATCH, 192, 27, 27, 13, 13);
    }

    // ---- conv3 ----
    {
        int total = 8 * 169 * 1728;
        im2col_conv3<<<(total + 255) / 256, 256, 0, stream>>>(pool2, col3);
        dim3 grid(6, (8 * 169 + BM - 1) / BM);
        gemm_fp32_t<64><<<grid, 256, 0, stream>>>(
            col3, wt3, featN, 8 * 169, 384, 1728,
            c3b, nullptr, nullptr, nullptr, nullptr, 0);
    }

    // ---- ROI pool (NHWC feat) + zero padding row ----
    {
        int total = NROI * C_FEAT;
        roi_pool_kernel<<<(total + 255) / 256, 256, 0, stream>>>(featN, bboxes, own, NROI, C_FEAT, 13, 13);
        zero_kernel<<<(N_VIS + 255) / 256, 256, 0, stream>>>(own + (size_t)NROI * N_VIS, N_VIS);
    }

    // ---- encoder on padded rows (1025) ----
    {
        dim3 grid((HID + 63) / 64, (NROI + 1 + BM - 1) / BM);
        gemm_fp32_t<64><<<grid, 256, 0, stream>>>(own, enc_w1, mid, NROI + 1, HID, N_VIS,
                                                  enc_b1, enc_g, enc_be, enc_m, enc_v, 1);
        gemm_fp32_t<64><<<grid, 256, 0, stream>>>(mid, enc_w2, enc_all, NROI + 1, HID, HID,
                                                  enc_b2, nullptr, nullptr, nullptr, nullptr, 0);
    }

    // ---- attention + combined assembly (overwrites conv scratch region) ----
    proj_kernel<<<NROI + 1, 128, 0, stream>>>(enc_all, att_w, s_own, proj_hi, NROI + 1, HID, NROI);
    att_combine_kernel<<<NROI, 512, 0, stream>>>(enc_all, ci, s_own, proj_hi, att_b,
                                                 own, bboxes, combined, NROI, HID);

    // ---- decoder ----
    {
        dim3 grid((NTOT + 127) / 128, (NROI + BM - 1) / BM);
        gemm_fp32_t<128><<<grid, 256, 0, stream>>>(combined, dec_w1, hbuf, NROI, NTOT, NTOT,
                                                   dec_b1, dec_g, dec_be, dec_m, dec_v, 1);
    }
    gemv4_kernel<<<NROI, 256, 0, stream>>>(hbuf, dec_w2, dec_b2, out, NTOT);
}

// Round 3
// 1351.716 us; speedup vs baseline: 2.0812x; 1.4846x over previous
//
#include <hip/hip_runtime.h>
#include <hip/hip_bf16.h>
#include <math.h>

#define C_FEAT 384
#define N_VIS (C_FEAT * 9)       // 3456
#define HID 300
#define BN_EPS 1e-5f
#define BATCH 8
#define NROI 1024
#define K2 10
#define NTOT (N_VIS + HID + 4)   // 3760
#define KPAD_DEC 3776            // 3760 padded to 32

typedef _Float16 f16;
typedef f16 f16x8 __attribute__((ext_vector_type(8)));
typedef float f32x4 __attribute__((ext_vector_type(4)));
typedef int i32x4 __attribute__((ext_vector_type(4)));

// ====================== split fp32 -> (hi,lo) fp16, row-major, col-padded ======================
__global__ void split_rowmajor(const float* __restrict__ in, f16* __restrict__ oh,
                               f16* __restrict__ ol, int R, int C, int Cpad)
{
    int idx = blockIdx.x * blockDim.x + threadIdx.x;
    if (idx >= R * Cpad) return;
    int r = idx / Cpad, c = idx % Cpad;
    float v = (c < C) ? in[(size_t)r * C + c] : 0.f;
    f16 h = (f16)v;
    oh[idx] = h;
    ol[idx] = (f16)(v - (float)h);
}

// ====================== transpose + split: Bt[n][k] = W[k][nc0+n], k-padded ======================
__global__ void transpose_split(const float* __restrict__ W, int K, int Ntot, int nc0, int NC,
                                int Kpad, f16* __restrict__ Bh, f16* __restrict__ Bl)
{
    __shared__ float T[32][33];
    int k0 = blockIdx.x * 32, n0 = blockIdx.y * 32;
    int tc = threadIdx.x & 31, tr = threadIdx.x >> 5;   // tr 0..7
    #pragma unroll
    for (int i = 0; i < 4; ++i) {
        int r = tr + i * 8;
        int gk = k0 + r, nloc = n0 + tc, gn = nc0 + nloc;
        float v = 0.f;
        if (gk < K && nloc < NC && gn < Ntot) v = W[(size_t)gk * Ntot + gn];
        T[r][tc] = v;
    }
    __syncthreads();
    #pragma unroll
    for (int i = 0; i < 4; ++i) {
        int nr = tr + i * 8;
        int n = n0 + nr;
        if (n >= NC) continue;
        float v = T[tc][nr];
        f16 h = (f16)v;
        size_t o = (size_t)n * Kpad + k0 + tc;
        Bh[o] = h;
        Bl[o] = (f16)(v - (float)h);
    }
}

// ====================== im2col (fp16 hi/lo), k-order = ic*KS*KS + kh*KS + kw ======================
__global__ void im2col1_f16(const float* __restrict__ img, f16* __restrict__ ch, f16* __restrict__ cl,
                            int b0, int nb)   // out rows nb*3025, kpad 384
{
    int idx = blockIdx.x * blockDim.x + threadIdx.x;
    int total = nb * 3025 * 384;
    if (idx >= total) return;
    int k = idx % 384, r = idx / 384;
    int ow = r % 55, t = r / 55;
    int oh = t % 55, bi = t / 55;
    float v = 0.f;
    if (k < 363) {
        int ic = k / 121, q = k % 121;
        int kh = q / 11, kw = q % 11;
        int ih = oh * 4 - 2 + kh, iw = ow * 4 - 2 + kw;
        if (ih >= 0 && ih < 224 && iw >= 0 && iw < 224)
            v = img[(((size_t)(b0 + bi) * 3 + ic) * 224 + ih) * 224 + iw];
    }
    f16 h = (f16)v;
    ch[idx] = h;
    cl[idx] = (f16)(v - (float)h);
}

__global__ void im2col2_f16(const float* __restrict__ in, f16* __restrict__ ch, f16* __restrict__ cl,
                            int b0, int nb)   // in pool1 NHWC [8][27][27][64]; k = ic*25+kh*5+kw (1600)
{
    int idx = blockIdx.x * blockDim.x + threadIdx.x;
    int total = nb * 729 * 1600;
    if (idx >= total) return;
    int k = idx % 1600, r = idx / 1600;
    int ow = r % 27, t = r / 27;
    int oh = t % 27, bi = t / 27;
    int ic = k / 25, q = k % 25;
    int kh = q / 5, kw = q % 5;
    int ih = oh - 2 + kh, iw = ow - 2 + kw;
    float v = 0.f;
    if (ih >= 0 && ih < 27 && iw >= 0 && iw < 27)
        v = in[(((size_t)(b0 + bi) * 27 + ih) * 27 + iw) * 64 + ic];
    f16 h = (f16)v;
    ch[idx] = h;
    cl[idx] = (f16)(v - (float)h);
}

__global__ void im2col3_f16(const float* __restrict__ in, f16* __restrict__ ch, f16* __restrict__ cl)
{   // in pool2 NHWC [8][13][13][192]; k = ic*9+kh*3+kw (1728)
    int idx = blockIdx.x * blockDim.x + threadIdx.x;
    int total = 8 * 169 * 1728;
    if (idx >= total) return;
    int k = idx % 1728, r = idx / 1728;
    int ow = r % 13, t = r / 13;
    int oh = t % 13, bi = t / 13;
    int ic = k / 9, q = k % 9;
    int kh = q / 3, kw = q % 3;
    int ih = oh - 1 + kh, iw = ow - 1 + kw;
    float v = 0.f;
    if (ih >= 0 && ih < 13 && iw >= 0 && iw < 13)
        v = in[(((size_t)bi * 13 + ih) * 13 + iw) * 192 + ic];
    f16 h = (f16)v;
    ch[idx] = h;
    cl[idx] = (f16)(v - (float)h);
}

// ====================== f16x3 MFMA GEMM: C(MxN) = A(MxK) @ Bt(NxK)^T ======================
// A given as (Ah,Al) row-major stride lda; B given transposed (Bh,Bl) [N][K] stride ldb.
// MODE 0: +bias ; 1: bias+BN+relu ; 2: bias+relu
#define LDH 40   // LDS row pitch in halves (32 + 8 pad)
template<int MODE>
__global__ __launch_bounds__(256) void gemm_f16x3(
    const f16* __restrict__ Ah, const f16* __restrict__ Al, int lda,
    const f16* __restrict__ Bh, const f16* __restrict__ Bl, int ldb,
    float* __restrict__ C, int ldc, int M, int N, int K,
    const float* __restrict__ bias, const float* __restrict__ g,
    const float* __restrict__ be, const float* __restrict__ mean,
    const float* __restrict__ var)
{
    __shared__ f16 sAh[128 * LDH], sAl[128 * LDH], sBh[128 * LDH], sBl[128 * LDH];
    int tid = threadIdx.x;
    int lane = tid & 63, w = tid >> 6;
    int wr = w >> 1, wc = w & 1;
    int bm = blockIdx.y * 128, bn = blockIdx.x * 128;

    f32x4 acc[4][4];
    #pragma unroll
    for (int i = 0; i < 4; ++i)
        #pragma unroll
        for (int j = 0; j < 4; ++j) acc[i][j] = (f32x4){0.f, 0.f, 0.f, 0.f};

    // staging: thread t covers row = t>>1 (0..127), 16 halves at ko = (t&1)*16
    int srow = tid >> 1, sko = (tid & 1) * 16;
    int arow = bm + srow, brow = bn + srow;
    bool aval = arow < M, bval = brow < N;
    const f16* pAh = Ah + (size_t)(aval ? arow : 0) * lda + sko;
    const f16* pAl = Al + (size_t)(aval ? arow : 0) * lda + sko;
    const f16* pBh = Bh + (size_t)(bval ? brow : 0) * ldb + sko;
    const f16* pBl = Bl + (size_t)(bval ? brow : 0) * ldb + sko;
    int sbase = srow * LDH + sko;

    int kfo = (lane >> 4) * 8;
    int rr = lane & 15;

    const i32x4 zz = {0, 0, 0, 0};
    for (int k0 = 0; k0 < K; k0 += 32) {
        i32x4 rah0 = zz, rah1 = zz, ral0 = zz, ral1 = zz;
        i32x4 rbh0 = zz, rbh1 = zz, rbl0 = zz, rbl1 = zz;
        if (aval) {
            rah0 = *(const i32x4*)(pAh + k0);
            rah1 = *(const i32x4*)(pAh + k0 + 8);
            ral0 = *(const i32x4*)(pAl + k0);
            ral1 = *(const i32x4*)(pAl + k0 + 8);
        }
        if (bval) {
            rbh0 = *(const i32x4*)(pBh + k0);
            rbh1 = *(const i32x4*)(pBh + k0 + 8);
            rbl0 = *(const i32x4*)(pBl + k0);
            rbl1 = *(const i32x4*)(pBl + k0 + 8);
        }
        __syncthreads();
        *(i32x4*)&sAh[sbase] = rah0;  *(i32x4*)&sAh[sbase + 8] = rah1;
        *(i32x4*)&sAl[sbase] = ral0;  *(i32x4*)&sAl[sbase + 8] = ral1;
        *(i32x4*)&sBh[sbase] = rbh0;  *(i32x4*)&sBh[sbase + 8] = rbh1;
        *(i32x4*)&sBl[sbase] = rbl0;  *(i32x4*)&sBl[sbase + 8] = rbl1;
        __syncthreads();

        f16x8 fah[4], fal[4], fbh[4], fbl[4];
        #pragma unroll
        for (int m = 0; m < 4; ++m) {
            int row = wr * 64 + m * 16 + rr;
            fah[m] = *(const f16x8*)&sAh[row * LDH + kfo];
            fal[m] = *(const f16x8*)&sAl[row * LDH + kfo];
        }
        #pragma unroll
        for (int n = 0; n < 4; ++n) {
            int row = wc * 64 + n * 16 + rr;
            fbh[n] = *(const f16x8*)&sBh[row * LDH + kfo];
            fbl[n] = *(const f16x8*)&sBl[row * LDH + kfo];
        }
        #pragma unroll
        for (int m = 0; m < 4; ++m)
            #pragma unroll
            for (int n = 0; n < 4; ++n) {
                acc[m][n] = __builtin_amdgcn_mfma_f32_16x16x32_f16(fah[m], fbh[n], acc[m][n], 0, 0, 0);
                acc[m][n] = __builtin_amdgcn_mfma_f32_16x16x32_f16(fah[m], fbl[n], acc[m][n], 0, 0, 0);
                acc[m][n] = __builtin_amdgcn_mfma_f32_16x16x32_f16(fal[m], fbh[n], acc[m][n], 0, 0, 0);
            }
    }

    // epilogue: C row = (lane>>4)*4 + r within fragment, col = lane&15
    int crl = lane >> 4;
    #pragma unroll
    for (int m = 0; m < 4; ++m) {
        #pragma unroll
        for (int n = 0; n < 4; ++n) {
            int gn = bn + wc * 64 + n * 16 + rr;
            if (gn >= N) continue;
            #pragma unroll
            for (int r = 0; r < 4; ++r) {
                int gm = bm + wr * 64 + m * 16 + crl * 4 + r;
                if (gm >= M) continue;
                float v = acc[m][n][r] + bias[gn];
                if (MODE == 1) {
                    float s = g[gn] / sqrtf(var[gn] + BN_EPS);
                    v = (v - mean[gn]) * s + be[gn];
                    v = fmaxf(v, 0.f);
                } else if (MODE == 2) {
                    v = fmaxf(v, 0.f);
                }
                C[(size_t)gm * ldc + gn] = v;
            }
        }
    }
}

// ====================== NHWC 3x3 stride2 VALID maxpool ======================
__global__ void maxpool3s2_nhwc(const float* __restrict__ in, float* __restrict__ out,
                                int Bn, int C, int Hin, int Win, int Hout, int Wout)
{
    int idx = blockIdx.x * blockDim.x + threadIdx.x;
    int total = Bn * Hout * Wout * C;
    if (idx >= total) return;
    int c = idx % C, t = idx / C;
    int ow = t % Wout; t /= Wout;
    int oh = t % Hout; int b = t / Hout;
    const float* base = in + (((size_t)b * Hin + oh * 2) * Win + ow * 2) * C + c;
    float v = -INFINITY;
    #pragma unroll
    for (int kh = 0; kh < 3; ++kh)
        #pragma unroll
        for (int kw = 0; kw < 3; ++kw)
            v = fmaxf(v, base[((size_t)kh * Win + kw) * C]);
    out[idx] = v;
}

// ====================== ROI max-pool, NHWC feat ======================
__global__ void roi_pool_kernel(const float* __restrict__ feat, const float* __restrict__ bboxes,
                                float* __restrict__ own, int N, int C, int H, int W)
{
    int idx = blockIdx.x * blockDim.x + threadIdx.x;
    if (idx >= N * C) return;
    int n = idx / C, c = idx % C;
    const float* bb = bboxes + (size_t)n * 5;
    int img = (int)bb[0];
    const float SC = 13.0f / 224.0f;
    int x1 = (int)rintf(bb[1] * SC);
    int y1 = (int)rintf(bb[2] * SC);
    int x2 = (int)rintf(bb[3] * SC);
    int y2 = (int)rintf(bb[4] * SC);
    int roi_w = max(x2 - x1 + 1, 1);
    int roi_h = max(y2 - y1 + 1, 1);
    const float* f = feat + (size_t)img * H * W * C + c;
    float* o = own + (size_t)n * (C * 9) + (size_t)c * 9;
    for (int ph = 0; ph < 3; ++ph) {
        int hstart = min(max(y1 + (ph * roi_h) / 3, 0), H);
        int hend   = min(max(y1 + ((ph + 1) * roi_h + 2) / 3, 0), H);
        for (int pw = 0; pw < 3; ++pw) {
            int wstart = min(max(x1 + (pw * roi_w) / 3, 0), W);
            int wend   = min(max(x1 + ((pw + 1) * roi_w + 2) / 3, 0), W);
            float v;
            if (hend <= hstart || wend <= wstart) {
                v = 0.f;
            } else {
                v = -INFINITY;
                for (int hh = hstart; hh < hend; ++hh)
                    for (int ww = wstart; ww < wend; ++ww)
                        v = fmaxf(v, f[((size_t)hh * W + ww) * C]);
            }
            o[ph * 3 + pw] = v;
        }
    }
}

__global__ void zero_kernel(float* __restrict__ p, int n)
{
    int i = blockIdx.x * blockDim.x + threadIdx.x;
    if (i < n) p[i] = 0.f;
}

// ====================== fp32 tiled GEMM (small, enc2 only) ======================
#define BM 64
#define BK 16
__global__ __launch_bounds__(256) void gemm_fp32_64(
    const float* __restrict__ A, const float* __restrict__ B, float* __restrict__ C,
    int M, int N, int K, const float* __restrict__ bias)
{
    __shared__ float As[BK][BM];
    __shared__ float Bs[BK][64];
    int bm = blockIdx.y * BM, bn = blockIdx.x * 64;
    int tid = threadIdx.x;
    int tx = tid & 15, ty = tid >> 4;
    float acc[4][4] = {};

    for (int k0 = 0; k0 < K; k0 += BK) {
        {
            int m = tid >> 2, kk = (tid & 3) * 4;
            int gm = bm + m;
            #pragma unroll
            for (int j = 0; j < 4; ++j) {
                int gk = k0 + kk + j;
                As[kk + j][m] = (gm < M && gk < K) ? A[(size_t)gm * K + gk] : 0.f;
            }
        }
        {
            int kk = tid >> 4, nb = (tid & 15) * 4;
            int gk = k0 + kk;
            #pragma unroll
            for (int j = 0; j < 4; ++j) {
                int gn = bn + nb + j;
                Bs[kk][nb + j] = (gk < K && gn < N) ? B[(size_t)gk * N + gn] : 0.f;
            }
        }
        __syncthreads();
        #pragma unroll
        for (int kk = 0; kk < BK; ++kk) {
            float a[4], b[4];
            #pragma unroll
            for (int i = 0; i < 4; ++i) a[i] = As[kk][ty * 4 + i];
            #pragma unroll
            for (int j = 0; j < 4; ++j) b[j] = Bs[kk][tx * 4 + j];
            #pragma unroll
            for (int i = 0; i < 4; ++i)
                #pragma unroll
                for (int j = 0; j < 4; ++j)
                    acc[i][j] += a[i] * b[j];
        }
        __syncthreads();
    }
    #pragma unroll
    for (int i = 0; i < 4; ++i) {
        int gm = bm + ty * 4 + i;
        if (gm >= M) continue;
        #pragma unroll
        for (int j = 0; j < 4; ++j) {
            int gn = bn + tx * 4 + j;
            if (gn >= N) continue;
            C[(size_t)gm * N + gn] = acc[i][j] + bias[gn];
        }
    }
}

// ====================== attention projections ======================
__global__ __launch_bounds__(128) void proj_kernel(
    const float* __restrict__ enc_all, const float* __restrict__ att_w,
    float* __restrict__ s_own, float* __restrict__ proj_hi, int R, int H, int Nroi)
{
    int r = blockIdx.x, tid = threadIdx.x;
    const float* row = enc_all + (size_t)r * H;
    float plo = 0.f, phi = 0.f;
    for (int hh = tid; hh < H; hh += 128) {
        float v = row[hh];
        plo += v * att_w[hh];
        phi += v * att_w[H + hh];
    }
    __shared__ float slo[128], shi[128];
    slo[tid] = plo; shi[tid] = phi;
    __syncthreads();
    for (int s = 64; s > 0; s >>= 1) {
        if (tid < s) { slo[tid] += slo[tid + s]; shi[tid] += shi[tid + s]; }
        __syncthreads();
    }
    if (tid == 0) {
        if (r < Nroi) s_own[r] = slo[0];
        proj_hi[r] = shi[0];
    }
}

// ====================== attention softmax + ctx_rep + assemble combined row ======================
__global__ __launch_bounds__(512) void att_combine_kernel(
    const float* __restrict__ enc_all, const int* __restrict__ ci,
    const float* __restrict__ s_own, const float* __restrict__ proj_hi,
    const float* __restrict__ att_b, const float* __restrict__ own,
    const float* __restrict__ bboxes, float* __restrict__ combined,
    int N, int H)
{
    int n = blockIdx.x, tid = threadIdx.x;
    __shared__ float wts[K2];
    __shared__ int rows[K2];
    if (tid < K2) {
        int idx = ci[(size_t)n * K2 + tid];
        int row = (idx < 0) ? N : idx;
        rows[tid] = row;
        wts[tid] = s_own[n] + proj_hi[row] + att_b[0];
    }
    __syncthreads();
    if (tid == 0) {
        float mx = wts[0];
        #pragma unroll
        for (int k = 1; k < K2; ++k) mx = fmaxf(mx, wts[k]);
        float sum = 0.f;
        float e[K2];
        #pragma unroll
        for (int k = 0; k < K2; ++k) { e[k] = expf(wts[k] - mx); sum += e[k]; }
        float inv = 1.f / sum;
        #pragma unroll
        for (int k = 0; k < K2; ++k) wts[k] = e[k] * inv;
    }
    __syncthreads();

    float* crow = combined + (size_t)n * NTOT;
    if (tid < H) {
        float acc = 0.f;
        #pragma unroll
        for (int k = 0; k < K2; ++k)
            acc += wts[k] * enc_all[(size_t)rows[k] * H + tid];
        crow[N_VIS + tid] = acc;
    }
    const float* orow = own + (size_t)n * N_VIS;
    for (int j = tid; j < N_VIS; j += 512) crow[j] = orow[j];
    if (tid >= 508) {
        int j = tid - 508;
        float x1 = bboxes[(size_t)n * 5 + 1];
        float y1 = bboxes[(size_t)n * 5 + 2];
        float x2 = bboxes[(size_t)n * 5 + 3];
        float y2 = bboxes[(size_t)n * 5 + 4];
        float vals[4] = { x1, y1, x2 - x1, y2 - y1 };
        crow[N_VIS + HID + j] = vals[j];
    }
}

// ====================== out(1024,4) = h @ w2 + b2 ======================
__global__ __launch_bounds__(256) void gemv4_kernel(
    const float* __restrict__ h, const float* __restrict__ w2,
    const float* __restrict__ b2, float* __restrict__ out, int K)
{
    int m = blockIdx.x, tid = threadIdx.x;
    const float* hr = h + (size_t)m * K;
    float a0 = 0.f, a1 = 0.f, a2 = 0.f, a3 = 0.f;
    for (int k = tid; k < K; k += 256) {
        float x = hr[k];
        const float* wr = w2 + (size_t)k * 4;
        a0 += x * wr[0]; a1 += x * wr[1]; a2 += x * wr[2]; a3 += x * wr[3];
    }
    __shared__ float red[256][4];
    red[tid][0] = a0; red[tid][1] = a1; red[tid][2] = a2; red[tid][3] = a3;
    __syncthreads();
    for (int s = 128; s > 0; s >>= 1) {
        if (tid < s) {
            #pragma unroll
            for (int j = 0; j < 4; ++j) red[tid][j] += red[tid + s][j];
        }
        __syncthreads();
    }
    if (tid < 4) out[(size_t)m * 4 + tid] = red[0][tid] + b2[tid];
}

extern "C" void kernel_launch(void* const* d_in, const int* in_sizes, int n_in,
                              void* d_out, int out_size, void* d_ws, size_t ws_size,
                              hipStream_t stream)
{
    const float* images = (const float*)d_in[0];
    const float* bboxes = (const float*)d_in[1];
    const int*   ci     = (const int*)  d_in[2];
    const float* c1w = (const float*)d_in[3];
    const float* c1b = (const float*)d_in[4];
    const float* c2w = (const float*)d_in[5];
    const float* c2b = (const float*)d_in[6];
    const float* c3w = (const float*)d_in[7];
    const float* c3b = (const float*)d_in[8];
    const float* enc_w1 = (const float*)d_in[9];
    const float* enc_b1 = (const float*)d_in[10];
    const float* enc_g  = (const float*)d_in[11];
    const float* enc_be = (const float*)d_in[12];
    const float* enc_m  = (const float*)d_in[13];
    const float* enc_v  = (const float*)d_in[14];
    const float* enc_w2 = (const float*)d_in[15];
    const float* enc_b2 = (const float*)d_in[16];
    const float* att_w  = (const float*)d_in[17];
    const float* att_b  = (const float*)d_in[18];
    const float* dec_w1 = (const float*)d_in[19];
    const float* dec_b1 = (const float*)d_in[20];
    const float* dec_g  = (const float*)d_in[21];
    const float* dec_be = (const float*)d_in[22];
    const float* dec_m  = (const float*)d_in[23];
    const float* dec_v  = (const float*)d_in[24];
    const float* dec_w2 = (const float*)d_in[25];
    const float* dec_b2 = (const float*)d_in[26];
    float* out = (float*)d_out;

    float* ws = (float*)d_ws;
    size_t off = 0;
    auto alloc = [&](size_t n) { float* p = ws + off; off += (n + 255) & ~(size_t)255; return p; };

    float* own      = alloc((size_t)(NROI + 1) * N_VIS);       // 3,542,400
    float* featN    = alloc((size_t)BATCH * 13 * 13 * C_FEAT); // 519,168
    float* mid      = alloc((size_t)(NROI + 1) * HID);
    float* enc_all  = alloc((size_t)(NROI + 1) * HID);
    float* s_own    = alloc(NROI);
    float* proj_hi  = alloc(NROI + 1);
    float* combined = alloc((size_t)NROI * NTOT);              // 3,850,240
    float* hbuf     = alloc((size_t)NROI * NTOT);              // 3,850,240

    // ======== scratch region S = combined..(combined+hbuf span is NOT free; only combined) ========
    // During conv/enc phases BOTH combined and hbuf are dead -> 7,700,480 floats of scratch.
    float* S = combined;

    // conv-phase layout (float offsets into S):
    float* conv1o = S;                     // 1,548,800 NHWC 8x55x55x64
    float* conv2o = S;                     // 1,119,744 NHWC 8x27x27x192 (after conv1o dead)
    float* pool1  = S + 1548800;           //   373,248 NHWC 8x27x27x64
    float* pool2  = S + 1548800;           //   259,584 NHWC 8x13x13x192 (after pool1 dead)
    f16* col_h    = (f16*)(S + 1922048);   // conv1: 2,323,200 fl worth; conv2: 2,332,800; conv3: 1,168,128
    f16* col1_l   = (f16*)(S + 4245248);
    f16* col2_l   = (f16*)(S + 4254848);
    f16* col3_l   = (f16*)(S + 3090176);
    // weight splits at tail of scratch:
    f16* wt1_h = (f16*)(S + 6651904);              // 24,576 halves
    f16* wt1_l = wt1_h + 24576;
    f16* wt2_h = wt1_l + 24576;                    // 307,200 halves
    f16* wt2_l = wt2_h + 307200;
    f16* wt3_h = wt2_l + 307200;                   // 663,552 halves
    f16* wt3_l = wt3_h + 663552;                   // ends at +1,990,656 halves = 995,328 fl -> ok

    // ---- weight splits ----
    split_rowmajor<<<(64 * 384 + 255) / 256, 256, 0, stream>>>(c1w, wt1_h, wt1_l, 64, 363, 384);
    split_rowmajor<<<(192 * 1600 + 255) / 256, 256, 0, stream>>>(c2w, wt2_h, wt2_l, 192, 1600, 1600);
    split_rowmajor<<<(384 * 1728 + 255) / 256, 256, 0, stream>>>(c3w, wt3_h, wt3_l, 384, 1728, 1728);

    // ---- conv1: 2 chunks of 4 images ----
    for (int ch = 0; ch < 2; ++ch) {
        int b0 = ch * 4, nb = 4;
        int total = nb * 3025 * 384;
        im2col1_f16<<<(total + 255) / 256, 256, 0, stream>>>(images, col_h, col1_l, b0, nb);
        dim3 grid(1, (nb * 3025 + 127) / 128);
        gemm_f16x3<2><<<grid, 256, 0, stream>>>(
            col_h, col1_l, 384, wt1_h, wt1_l, 384,
            conv1o + (size_t)b0 * 3025 * 64, 64, nb * 3025, 64, 384,
            c1b, nullptr, nullptr, nullptr, nullptr);
    }
    maxpool3s2_nhwc<<<(BATCH * 27 * 27 * 64 + 255) / 256, 256, 0, stream>>>(
        conv1o, pool1, BATCH, 64, 55, 55, 27, 27);

    // ---- conv2: 2 chunks of 4 images ----
    for (int ch = 0; ch < 2; ++ch) {
        int b0 = ch * 4, nb = 4;
        int total = nb * 729 * 1600;
        im2col2_f16<<<(total + 255) / 256, 256, 0, stream>>>(pool1, col_h, col2_l, b0, nb);
        dim3 grid(2, (nb * 729 + 127) / 128);
        gemm_f16x3<2><<<grid, 256, 0, stream>>>(
            col_h, col2_l, 1600, wt2_h, wt2_l, 1600,
            conv2o + (size_t)b0 * 729 * 192, 192, nb * 729, 192, 1600,
            c2b, nullptr, nullptr, nullptr, nullptr);
    }
    maxpool3s2_nhwc<<<(BATCH * 13 * 13 * 192 + 255) / 256, 256, 0, stream>>>(
        conv2o, pool2, BATCH, 192, 27, 27, 13, 13);

    // ---- conv3 ----
    {
        int total = 8 * 169 * 1728;
        im2col3_f16<<<(total + 255) / 256, 256, 0, stream>>>(pool2, col_h, col3_l);
        dim3 grid(3, (8 * 169 + 127) / 128);
        gemm_f16x3<0><<<grid, 256, 0, stream>>>(
            col_h, col3_l, 1728, wt3_h, wt3_l, 1728,
            featN, 384, 8 * 169, 384, 1728,
            c3b, nullptr, nullptr, nullptr, nullptr);
    }

    // ---- ROI pool + zero pad row ----
    roi_pool_kernel<<<(NROI * C_FEAT + 255) / 256, 256, 0, stream>>>(featN, bboxes, own, NROI, C_FEAT, 13, 13);
    zero_kernel<<<(N_VIS + 255) / 256, 256, 0, stream>>>(own + (size_t)NROI * N_VIS, N_VIS);

    // ---- encoder ----
    f16* own_h  = (f16*)(S + 0);           // 1,771,200 fl
    f16* own_l  = (f16*)(S + 1771200);
    f16* encB_h = (f16*)(S + 3542400);     // 518,400 fl
    f16* encB_l = (f16*)(S + 4060800);     // ends 4,579,200
    split_rowmajor<<<((NROI + 1) * N_VIS + 255) / 256, 256, 0, stream>>>(
        own, own_h, own_l, NROI + 1, N_VIS, N_VIS);
    {
        dim3 tg((N_VIS + 31) / 32, (HID + 31) / 32);
        transpose_split<<<tg, 256, 0, stream>>>(enc_w1, N_VIS, HID, 0, HID, N_VIS, encB_h, encB_l);
    }
    {
        dim3 grid((HID + 127) / 128, (NROI + 1 + 127) / 128);
        gemm_f16x3<1><<<grid, 256, 0, stream>>>(
            own_h, own_l, N_VIS, encB_h, encB_l, N_VIS,
            mid, HID, NROI + 1, HID, N_VIS,
            enc_b1, enc_g, enc_be, enc_m, enc_v);
    }
    {
        dim3 grid((HID + 63) / 64, (NROI + 1 + BM - 1) / BM);
        gemm_fp32_64<<<grid, 256, 0, stream>>>(mid, enc_w2, enc_all, NROI + 1, HID, HID, enc_b2);
    }

    // ---- attention + combined (overwrites own_h/encB scratch) ----
    proj_kernel<<<NROI + 1, 128, 0, stream>>>(enc_all, att_w, s_own, proj_hi, NROI + 1, HID, NROI);
    att_combine_kernel<<<NROI, 512, 0, stream>>>(enc_all, ci, s_own, proj_hi, att_b,
                                                 own, bboxes, combined, NROI, HID);

    // ---- decoder: split combined (into dead own region), then 4 N-chunks of W1 ----
    f16* comb_h = (f16*)own;               // 1,933,312 fl
    f16* comb_l = (f16*)(own + 1933312);   // ends own+3,866,624 (spills into dead featN: ok)
    split_rowmajor<<<(NROI * KPAD_DEC + 255) / 256, 256, 0, stream>>>(
        combined, comb_h, comb_l, NROI, NTOT, KPAD_DEC);

    f16* Btc_h = (f16*)(S + 0);            // 1,774,720 fl
    f16* Btc_l = (f16*)(S + 1774720);      // ends 3,549,440 <= combined alloc 3,850,240
    for (int c = 0; c < 4; ++c) {
        int nc0 = c * 940, NC = 940;
        dim3 tg(KPAD_DEC / 32, (NC + 31) / 32);
        transpose_split<<<tg, 256, 0, stream>>>(dec_w1, NTOT, NTOT, nc0, NC, KPAD_DEC, Btc_h, Btc_l);
        dim3 grid((NC + 127) / 128, NROI / 128);
        gemm_f16x3<1><<<grid, 256, 0, stream>>>(
            comb_h, comb_l, KPAD_DEC, Btc_h, Btc_l, KPAD_DEC,
            hbuf + nc0, NTOT, NROI, NC, KPAD_DEC,
            dec_b1 + nc0, dec_g + nc0, dec_be + nc0, dec_m + nc0, dec_v + nc0);
    }

    gemv4_kernel<<<NROI, 256, 0, stream>>>(hbuf, dec_w2, dec_b2, out, NTOT);
}

// Round 5
// 541.345 us; speedup vs baseline: 5.1967x; 2.4970x over previous
//
#include <hip/hip_runtime.h>
#include <hip/hip_bf16.h>
#include <math.h>

#define C_FEAT 384
#define N_VIS (C_FEAT * 9)       // 3456
#define HID 300
#define BN_EPS 1e-5f
#define BATCH 8
#define NROI 1024
#define K2 10
#define NTOT (N_VIS + HID + 4)   // 3760
#define KPAD_DEC 3776            // 3760 padded to 32

typedef _Float16 f16;
typedef f16 f16x8 __attribute__((ext_vector_type(8)));
typedef float f32x4 __attribute__((ext_vector_type(4)));
typedef int i32x4 __attribute__((ext_vector_type(4)));

// ====================== split fp32 -> (hi,lo) fp16, row-major, col-padded ======================
__global__ void split_rowmajor(const float* __restrict__ in, f16* __restrict__ oh,
                               f16* __restrict__ ol, int R, int C, int Cpad)
{
    int idx = blockIdx.x * blockDim.x + threadIdx.x;
    if (idx >= R * Cpad) return;
    int r = idx / Cpad, c = idx % Cpad;
    float v = (c < C) ? in[(size_t)r * C + c] : 0.f;
    f16 h = (f16)v;
    oh[idx] = h;
    ol[idx] = (f16)(v - (float)h);
}

// ====================== transpose + split: Bt[n][k] = W[k][nc0+n], k-padded ======================
__global__ void transpose_split(const float* __restrict__ W, int K, int Ntot, int nc0, int NC,
                                int Kpad, f16* __restrict__ Bh, f16* __restrict__ Bl)
{
    __shared__ float T[32][33];
    int k0 = blockIdx.x * 32, n0 = blockIdx.y * 32;
    int tc = threadIdx.x & 31, tr = threadIdx.x >> 5;   // tr 0..7
    #pragma unroll
    for (int i = 0; i < 4; ++i) {
        int r = tr + i * 8;
        int gk = k0 + r, nloc = n0 + tc, gn = nc0 + nloc;
        float v = 0.f;
        if (gk < K && nloc < NC && gn < Ntot) v = W[(size_t)gk * Ntot + gn];
        T[r][tc] = v;
    }
    __syncthreads();
    #pragma unroll
    for (int i = 0; i < 4; ++i) {
        int nr = tr + i * 8;
        int n = n0 + nr;
        if (n >= NC) continue;
        float v = T[tc][nr];
        f16 h = (f16)v;
        size_t o = (size_t)n * Kpad + k0 + tc;
        Bh[o] = h;
        Bl[o] = (f16)(v - (float)h);
    }
}

// ====================== im2col (fp16 hi/lo) ======================
__global__ void im2col1_f16(const float* __restrict__ img, f16* __restrict__ ch, f16* __restrict__ cl,
                            int b0, int nb)   // out rows nb*3025, kpad 384
{
    int idx = blockIdx.x * blockDim.x + threadIdx.x;
    int total = nb * 3025 * 384;
    if (idx >= total) return;
    int k = idx % 384, r = idx / 384;
    int ow = r % 55, t = r / 55;
    int oh = t % 55, bi = t / 55;
    float v = 0.f;
    if (k < 363) {
        int ic = k / 121, q = k % 121;
        int kh = q / 11, kw = q % 11;
        int ih = oh * 4 - 2 + kh, iw = ow * 4 - 2 + kw;
        if (ih >= 0 && ih < 224 && iw >= 0 && iw < 224)
            v = img[(((size_t)(b0 + bi) * 3 + ic) * 224 + ih) * 224 + iw];
    }
    f16 h = (f16)v;
    ch[idx] = h;
    cl[idx] = (f16)(v - (float)h);
}

__global__ void im2col2_f16(const float* __restrict__ in, f16* __restrict__ ch, f16* __restrict__ cl,
                            int b0, int nb)   // in pool1 NHWC [8][27][27][64]; k = ic*25+kh*5+kw (1600)
{
    int idx = blockIdx.x * blockDim.x + threadIdx.x;
    int total = nb * 729 * 1600;
    if (idx >= total) return;
    int k = idx % 1600, r = idx / 1600;
    int ow = r % 27, t = r / 27;
    int oh = t % 27, bi = t / 27;
    int ic = k / 25, q = k % 25;
    int kh = q / 5, kw = q % 5;
    int ih = oh - 2 + kh, iw = ow - 2 + kw;
    float v = 0.f;
    if (ih >= 0 && ih < 27 && iw >= 0 && iw < 27)
        v = in[(((size_t)(b0 + bi) * 27 + ih) * 27 + iw) * 64 + ic];
    f16 h = (f16)v;
    ch[idx] = h;
    cl[idx] = (f16)(v - (float)h);
}

__global__ void im2col3_f16(const float* __restrict__ in, f16* __restrict__ ch, f16* __restrict__ cl)
{   // in pool2 NHWC [8][13][13][192]; k = ic*9+kh*3+kw (1728)
    int idx = blockIdx.x * blockDim.x + threadIdx.x;
    int total = 8 * 169 * 1728;
    if (idx >= total) return;
    int k = idx % 1728, r = idx / 1728;
    int ow = r % 13, t = r / 13;
    int oh = t % 13, bi = t / 13;
    int ic = k / 9, q = k % 9;
    int kh = q / 3, kw = q % 3;
    int ih = oh - 1 + kh, iw = ow - 1 + kw;
    float v = 0.f;
    if (ih >= 0 && ih < 13 && iw >= 0 && iw < 13)
        v = in[(((size_t)bi * 13 + ih) * 13 + iw) * 192 + ic];
    f16 h = (f16)v;
    ch[idx] = h;
    cl[idx] = (f16)(v - (float)h);
}

// ====================== f16x3 MFMA GEMM with register prefetch ======================
// C(MxN) = A(MxK) @ Bt(NxK)^T ; A=(Ah,Al) row-major lda, Bt=(Bh,Bl) [N][K] ldb.
// MODE 0: +bias ; 1: bias+BN+relu ; 2: bias+relu
#define LDH 40   // LDS row pitch in halves (32 + 8 pad)
template<int TM, int TN, int MODE>
__global__ __launch_bounds__(256) void gemm_f16x3(
    const f16* __restrict__ Ah, const f16* __restrict__ Al, int lda,
    const f16* __restrict__ Bh, const f16* __restrict__ Bl, int ldb,
    float* __restrict__ C, int ldc, int M, int N, int K,
    const float* __restrict__ bias, const float* __restrict__ g,
    const float* __restrict__ be, const float* __restrict__ mean,
    const float* __restrict__ var)
{
    constexpr int WM = TM / 32;   // 16x16 frags per wave in M
    constexpr int WN = TN / 32;
    constexpr int AV = TM / 64;   // i32x4 staging loads per thread per array
    constexpr int BV = TN / 64;
    __shared__ f16 sAh[TM * LDH], sAl[TM * LDH], sBh[TN * LDH], sBl[TN * LDH];
    int tid = threadIdx.x;
    int lane = tid & 63, w = tid >> 6;
    int wr = w >> 1, wc = w & 1;
    int bm = blockIdx.y * TM, bn = blockIdx.x * TN;

    f32x4 acc[WM][WN];
    #pragma unroll
    for (int i = 0; i < WM; ++i)
        #pragma unroll
        for (int j = 0; j < WN; ++j) acc[i][j] = (f32x4){0.f, 0.f, 0.f, 0.f};

    // staging descriptors: seg -> row = seg>>2, ko = (seg&3)*8 (8 halves = 16B)
    const f16* pAh[AV]; const f16* pAl[AV]; int abase[AV]; bool avld[AV];
    #pragma unroll
    for (int i = 0; i < AV; ++i) {
        int seg = tid * AV + i;
        int row = seg >> 2, ko = (seg & 3) * 8;
        int gr = bm + row;
        avld[i] = gr < M;
        pAh[i] = Ah + (size_t)(avld[i] ? gr : 0) * lda + ko;
        pAl[i] = Al + (size_t)(avld[i] ? gr : 0) * lda + ko;
        abase[i] = row * LDH + ko;
    }
    const f16* pBh[BV]; const f16* pBl[BV]; int bbase[BV]; bool bvld[BV];
    #pragma unroll
    for (int i = 0; i < BV; ++i) {
        int seg = tid * BV + i;
        int row = seg >> 2, ko = (seg & 3) * 8;
        int gr = bn + row;
        bvld[i] = gr < N;
        pBh[i] = Bh + (size_t)(bvld[i] ? gr : 0) * ldb + ko;
        pBl[i] = Bl + (size_t)(bvld[i] ? gr : 0) * ldb + ko;
        bbase[i] = row * LDH + ko;
    }

    const i32x4 zz = {0, 0, 0, 0};
    i32x4 rAh[AV], rAl[AV], rBh[BV], rBl[BV];

    auto load_step = [&](int k0) {
        #pragma unroll
        for (int i = 0; i < AV; ++i) {
            rAh[i] = avld[i] ? *(const i32x4*)(pAh[i] + k0) : zz;
            rAl[i] = avld[i] ? *(const i32x4*)(pAl[i] + k0) : zz;
        }
        #pragma unroll
        for (int i = 0; i < BV; ++i) {
            rBh[i] = bvld[i] ? *(const i32x4*)(pBh[i] + k0) : zz;
            rBl[i] = bvld[i] ? *(const i32x4*)(pBl[i] + k0) : zz;
        }
    };
    load_step(0);

    int kfo = (lane >> 4) * 8;
    int rr = lane & 15;

    for (int k0 = 0; k0 < K; k0 += 32) {
        __syncthreads();
        #pragma unroll
        for (int i = 0; i < AV; ++i) {
            *(i32x4*)&sAh[abase[i]] = rAh[i];
            *(i32x4*)&sAl[abase[i]] = rAl[i];
        }
        #pragma unroll
        for (int i = 0; i < BV; ++i) {
            *(i32x4*)&sBh[bbase[i]] = rBh[i];
            *(i32x4*)&sBl[bbase[i]] = rBl[i];
        }
        __syncthreads();
        if (k0 + 32 < K) load_step(k0 + 32);   // prefetch next step into regs

        f16x8 fah[WM], fal[WM], fbh[WN], fbl[WN];
        #pragma unroll
        for (int m = 0; m < WM; ++m) {
            int row = wr * (WM * 16) + m * 16 + rr;
            fah[m] = *(const f16x8*)&sAh[row * LDH + kfo];
            fal[m] = *(const f16x8*)&sAl[row * LDH + kfo];
        }
        #pragma unroll
        for (int n = 0; n < WN; ++n) {
            int row = wc * (WN * 16) + n * 16 + rr;
            fbh[n] = *(const f16x8*)&sBh[row * LDH + kfo];
            fbl[n] = *(const f16x8*)&sBl[row * LDH + kfo];
        }
        #pragma unroll
        for (int m = 0; m < WM; ++m)
            #pragma unroll
            for (int n = 0; n < WN; ++n) {
                acc[m][n] = __builtin_amdgcn_mfma_f32_16x16x32_f16(fah[m], fbh[n], acc[m][n], 0, 0, 0);
                acc[m][n] = __builtin_amdgcn_mfma_f32_16x16x32_f16(fah[m], fbl[n], acc[m][n], 0, 0, 0);
                acc[m][n] = __builtin_amdgcn_mfma_f32_16x16x32_f16(fal[m], fbh[n], acc[m][n], 0, 0, 0);
            }
    }

    int crl = lane >> 4;
    #pragma unroll
    for (int m = 0; m < WM; ++m) {
        #pragma unroll
        for (int n = 0; n < WN; ++n) {
            int gn = bn + wc * (WN * 16) + n * 16 + rr;
            if (gn >= N) continue;
            #pragma unroll
            for (int r = 0; r < 4; ++r) {
                int gm = bm + wr * (WM * 16) + m * 16 + crl * 4 + r;
                if (gm >= M) continue;
                float v = acc[m][n][r] + bias[gn];
                if (MODE == 1) {
                    float s = g[gn] / sqrtf(var[gn] + BN_EPS);
                    v = (v - mean[gn]) * s + be[gn];
                    v = fmaxf(v, 0.f);
                } else if (MODE == 2) {
                    v = fmaxf(v, 0.f);
                }
                C[(size_t)gm * ldc + gn] = v;
            }
        }
    }
}

// ====================== NHWC 3x3 stride2 VALID maxpool ======================
__global__ void maxpool3s2_nhwc(const float* __restrict__ in, float* __restrict__ out,
                                int Bn, int C, int Hin, int Win, int Hout, int Wout)
{
    int idx = blockIdx.x * blockDim.x + threadIdx.x;
    int total = Bn * Hout * Wout * C;
    if (idx >= total) return;
    int c = idx % C, t = idx / C;
    int ow = t % Wout; t /= Wout;
    int oh = t % Hout; int b = t / Hout;
    const float* base = in + (((size_t)b * Hin + oh * 2) * Win + ow * 2) * C + c;
    float v = -INFINITY;
    #pragma unroll
    for (int kh = 0; kh < 3; ++kh)
        #pragma unroll
        for (int kw = 0; kw < 3; ++kw)
            v = fmaxf(v, base[((size_t)kh * Win + kw) * C]);
    out[idx] = v;
}

// ====================== ROI max-pool, NHWC feat ======================
__global__ void roi_pool_kernel(const float* __restrict__ feat, const float* __restrict__ bboxes,
                                float* __restrict__ own, int N, int C, int H, int W)
{
    int idx = blockIdx.x * blockDim.x + threadIdx.x;
    if (idx >= N * C) return;
    int n = idx / C, c = idx % C;
    const float* bb = bboxes + (size_t)n * 5;
    int img = (int)bb[0];
    const float SC = 13.0f / 224.0f;
    int x1 = (int)rintf(bb[1] * SC);
    int y1 = (int)rintf(bb[2] * SC);
    int x2 = (int)rintf(bb[3] * SC);
    int y2 = (int)rintf(bb[4] * SC);
    int roi_w = max(x2 - x1 + 1, 1);
    int roi_h = max(y2 - y1 + 1, 1);
    const float* f = feat + (size_t)img * H * W * C + c;
    float* o = own + (size_t)n * (C * 9) + (size_t)c * 9;
    for (int ph = 0; ph < 3; ++ph) {
        int hstart = min(max(y1 + (ph * roi_h) / 3, 0), H);
        int hend   = min(max(y1 + ((ph + 1) * roi_h + 2) / 3, 0), H);
        for (int pw = 0; pw < 3; ++pw) {
            int wstart = min(max(x1 + (pw * roi_w) / 3, 0), W);
            int wend   = min(max(x1 + ((pw + 1) * roi_w + 2) / 3, 0), W);
            float v;
            if (hend <= hstart || wend <= wstart) {
                v = 0.f;
            } else {
                v = -INFINITY;
                for (int hh = hstart; hh < hend; ++hh)
                    for (int ww = wstart; ww < wend; ++ww)
                        v = fmaxf(v, f[((size_t)hh * W + ww) * C]);
            }
            o[ph * 3 + pw] = v;
        }
    }
}

__global__ void zero_kernel(float* __restrict__ p, int n)
{
    int i = blockIdx.x * blockDim.x + threadIdx.x;
    if (i < n) p[i] = 0.f;
}

// ====================== fp32 tiled GEMM (enc2 only) ======================
#define BM 64
#define BK 16
__global__ __launch_bounds__(256) void gemm_fp32_64(
    const float* __restrict__ A, const float* __restrict__ B, float* __restrict__ C,
    int M, int N, int K, const float* __restrict__ bias)
{
    __shared__ float As[BK][BM];
    __shared__ float Bs[BK][64];
    int bm = blockIdx.y * BM, bn = blockIdx.x * 64;
    int tid = threadIdx.x;
    int tx = tid & 15, ty = tid >> 4;
    float acc[4][4] = {};

    for (int k0 = 0; k0 < K; k0 += BK) {
        {
            int m = tid >> 2, kk = (tid & 3) * 4;
            int gm = bm + m;
            #pragma unroll
            for (int j = 0; j < 4; ++j) {
                int gk = k0 + kk + j;
                As[kk + j][m] = (gm < M && gk < K) ? A[(size_t)gm * K + gk] : 0.f;
            }
        }
        {
            int kk = tid >> 4, nb = (tid & 15) * 4;
            int gk = k0 + kk;
            #pragma unroll
            for (int j = 0; j < 4; ++j) {
                int gn = bn + nb + j;
                Bs[kk][nb + j] = (gk < K && gn < N) ? B[(size_t)gk * N + gn] : 0.f;
            }
        }
        __syncthreads();
        #pragma unroll
        for (int kk = 0; kk < BK; ++kk) {
            float a[4], b[4];
            #pragma unroll
            for (int i = 0; i < 4; ++i) a[i] = As[kk][ty * 4 + i];
            #pragma unroll
            for (int j = 0; j < 4; ++j) b[j] = Bs[kk][tx * 4 + j];
            #pragma unroll
            for (int i = 0; i < 4; ++i)
                #pragma unroll
                for (int j = 0; j < 4; ++j)
                    acc[i][j] += a[i] * b[j];
        }
        __syncthreads();
    }
    #pragma unroll
    for (int i = 0; i < 4; ++i) {
        int gm = bm + ty * 4 + i;
        if (gm >= M) continue;
        #pragma unroll
        for (int j = 0; j < 4; ++j) {
            int gn = bn + tx * 4 + j;
            if (gn >= N) continue;
            C[(size_t)gm * N + gn] = acc[i][j] + bias[gn];
        }
    }
}

// ====================== attention projections ======================
__global__ __launch_bounds__(128) void proj_kernel(
    const float* __restrict__ enc_all, const float* __restrict__ att_w,
    float* __restrict__ s_own, float* __restrict__ proj_hi, int R, int H, int Nroi)
{
    int r = blockIdx.x, tid = threadIdx.x;
    const float* row = enc_all + (size_t)r * H;
    float plo = 0.f, phi = 0.f;
    for (int hh = tid; hh < H; hh += 128) {
        float v = row[hh];
        plo += v * att_w[hh];
        phi += v * att_w[H + hh];
    }
    __shared__ float slo[128], shi[128];
    slo[tid] = plo; shi[tid] = phi;
    __syncthreads();
    for (int s = 64; s > 0; s >>= 1) {
        if (tid < s) { slo[tid] += slo[tid + s]; shi[tid] += shi[tid + s]; }
        __syncthreads();
    }
    if (tid == 0) {
        if (r < Nroi) s_own[r] = slo[0];
        proj_hi[r] = shi[0];
    }
}

// ====================== attention softmax + ctx_rep + assemble combined row ======================
__global__ __launch_bounds__(512) void att_combine_kernel(
    const float* __restrict__ enc_all, const int* __restrict__ ci,
    const float* __restrict__ s_own, const float* __restrict__ proj_hi,
    const float* __restrict__ att_b, const float* __restrict__ own,
    const float* __restrict__ bboxes, float* __restrict__ combined,
    int N, int H)
{
    int n = blockIdx.x, tid = threadIdx.x;
    __shared__ float wts[K2];
    __shared__ int rows[K2];
    if (tid < K2) {
        int idx = ci[(size_t)n * K2 + tid];
        int row = (idx < 0) ? N : idx;
        rows[tid] = row;
        wts[tid] = s_own[n] + proj_hi[row] + att_b[0];
    }
    __syncthreads();
    if (tid == 0) {
        float mx = wts[0];
        #pragma unroll
        for (int k = 1; k < K2; ++k) mx = fmaxf(mx, wts[k]);
        float sum = 0.f;
        float e[K2];
        #pragma unroll
        for (int k = 0; k < K2; ++k) { e[k] = expf(wts[k] - mx); sum += e[k]; }
        float inv = 1.f / sum;
        #pragma unroll
        for (int k = 0; k < K2; ++k) wts[k] = e[k] * inv;
    }
    __syncthreads();

    float* crow = combined + (size_t)n * NTOT;
    if (tid < H) {
        float acc = 0.f;
        #pragma unroll
        for (int k = 0; k < K2; ++k)
            acc += wts[k] * enc_all[(size_t)rows[k] * H + tid];
        crow[N_VIS + tid] = acc;
    }
    const float* orow = own + (size_t)n * N_VIS;
    for (int j = tid; j < N_VIS; j += 512) crow[j] = orow[j];
    if (tid >= 508) {
        int j = tid - 508;
        float x1 = bboxes[(size_t)n * 5 + 1];
        float y1 = bboxes[(size_t)n * 5 + 2];
        float x2 = bboxes[(size_t)n * 5 + 3];
        float y2 = bboxes[(size_t)n * 5 + 4];
        float vals[4] = { x1, y1, x2 - x1, y2 - y1 };
        crow[N_VIS + HID + j] = vals[j];
    }
}

// ====================== out(1024,4) = h @ w2 + b2 ======================
__global__ __launch_bounds__(256) void gemv4_kernel(
    const float* __restrict__ h, const float* __restrict__ w2,
    const float* __restrict__ b2, float* __restrict__ out, int K)
{
    int m = blockIdx.x, tid = threadIdx.x;
    const float* hr = h + (size_t)m * K;
    float a0 = 0.f, a1 = 0.f, a2 = 0.f, a3 = 0.f;
    for (int k = tid; k < K; k += 256) {
        float x = hr[k];
        const float* wr = w2 + (size_t)k * 4;
        a0 += x * wr[0]; a1 += x * wr[1]; a2 += x * wr[2]; a3 += x * wr[3];
    }
    __shared__ float red[256][4];
    red[tid][0] = a0; red[tid][1] = a1; red[tid][2] = a2; red[tid][3] = a3;
    __syncthreads();
    for (int s = 128; s > 0; s >>= 1) {
        if (tid < s) {
            #pragma unroll
            for (int j = 0; j < 4; ++j) red[tid][j] += red[tid + s][j];
        }
        __syncthreads();
    }
    if (tid < 4) out[(size_t)m * 4 + tid] = red[0][tid] + b2[tid];
}

extern "C" void kernel_launch(void* const* d_in, const int* in_sizes, int n_in,
                              void* d_out, int out_size, void* d_ws, size_t ws_size,
                              hipStream_t stream)
{
    const float* images = (const float*)d_in[0];
    const float* bboxes = (const float*)d_in[1];
    const int*   ci     = (const int*)  d_in[2];
    const float* c1w = (const float*)d_in[3];
    const float* c1b = (const float*)d_in[4];
    const float* c2w = (const float*)d_in[5];
    const float* c2b = (const float*)d_in[6];
    const float* c3w = (const float*)d_in[7];
    const float* c3b = (const float*)d_in[8];
    const float* enc_w1 = (const float*)d_in[9];
    const float* enc_b1 = (const float*)d_in[10];
    const float* enc_g  = (const float*)d_in[11];
    const float* enc_be = (const float*)d_in[12];
    const float* enc_m  = (const float*)d_in[13];
    const float* enc_v  = (const float*)d_in[14];
    const float* enc_w2 = (const float*)d_in[15];
    const float* enc_b2 = (const float*)d_in[16];
    const float* att_w  = (const float*)d_in[17];
    const float* att_b  = (const float*)d_in[18];
    const float* dec_w1 = (const float*)d_in[19];
    const float* dec_b1 = (const float*)d_in[20];
    const float* dec_g  = (const float*)d_in[21];
    const float* dec_be = (const float*)d_in[22];
    const float* dec_m  = (const float*)d_in[23];
    const float* dec_v  = (const float*)d_in[24];
    const float* dec_w2 = (const float*)d_in[25];
    const float* dec_b2 = (const float*)d_in[26];
    float* out = (float*)d_out;

    float* ws = (float*)d_ws;
    size_t off = 0;
    auto alloc = [&](size_t n) { float* p = ws + off; off += (n + 255) & ~(size_t)255; return p; };

    float* own      = alloc((size_t)(NROI + 1) * N_VIS);       // 3,542,400
    float* featN    = alloc((size_t)BATCH * 13 * 13 * C_FEAT); // 519,168
    float* mid      = alloc((size_t)(NROI + 1) * HID);
    float* enc_all  = alloc((size_t)(NROI + 1) * HID);
    float* s_own    = alloc(NROI);
    float* proj_hi  = alloc(NROI + 1);
    float* combined = alloc((size_t)NROI * NTOT);              // 3,850,240
    float* hbuf     = alloc((size_t)NROI * NTOT);              // 3,850,240
    size_t base_off = off;                                     // = 12,379,904 floats

    // full-Bt decoder path needs 2 x 7,128,320 extra floats
    const size_t BTD_FL = 7128320;
    bool full_dec = (ws_size >= (base_off + 2 * BTD_FL) * sizeof(float));
    float* Btd_h_f = ws + base_off;
    float* Btd_l_f = ws + base_off + BTD_FL;

    // ======== scratch region S = combined (+hbuf where noted); dead until stage D ========
    float* S = combined;

    float* conv1o = S;                     // 1,548,800 NHWC 8x55x55x64
    float* conv2o = S;                     // 1,119,744 NHWC 8x27x27x192
    float* pool1  = S + 1548800;           //   373,248 NHWC 8x27x27x64
    float* pool2  = S + 1548800;           //   259,584 NHWC 8x13x13x192
    f16* col_h    = (f16*)(S + 1922048);
    f16* col1_l   = (f16*)(S + 4245248);
    f16* col2_l   = (f16*)(S + 4254848);
    f16* col3_l   = (f16*)(S + 3090176);
    f16* wt1_h = (f16*)(S + 6651904);
    f16* wt1_l = wt1_h + 24576;
    f16* wt2_h = wt1_l + 24576;
    f16* wt2_l = wt2_h + 307200;
    f16* wt3_h = wt2_l + 307200;
    f16* wt3_l = wt3_h + 663552;

    // ---- weight splits ----
    split_rowmajor<<<(64 * 384 + 255) / 256, 256, 0, stream>>>(c1w, wt1_h, wt1_l, 64, 363, 384);
    split_rowmajor<<<(192 * 1600 + 255) / 256, 256, 0, stream>>>(c2w, wt2_h, wt2_l, 192, 1600, 1600);
    split_rowmajor<<<(384 * 1728 + 255) / 256, 256, 0, stream>>>(c3w, wt3_h, wt3_l, 384, 1728, 1728);

    // ---- conv1: 2 chunks of 4 images (64x64 tiles: grid (1,190)) ----
    for (int ch = 0; ch < 2; ++ch) {
        int b0 = ch * 4, nb = 4;
        int total = nb * 3025 * 384;
        im2col1_f16<<<(total + 255) / 256, 256, 0, stream>>>(images, col_h, col1_l, b0, nb);
        dim3 grid(1, (nb * 3025 + 63) / 64);
        gemm_f16x3<64, 64, 2><<<grid, 256, 0, stream>>>(
            col_h, col1_l, 384, wt1_h, wt1_l, 384,
            conv1o + (size_t)b0 * 3025 * 64, 64, nb * 3025, 64, 384,
            c1b, nullptr, nullptr, nullptr, nullptr);
    }
    maxpool3s2_nhwc<<<(BATCH * 27 * 27 * 64 + 255) / 256, 256, 0, stream>>>(
        conv1o, pool1, BATCH, 64, 55, 55, 27, 27);

    // ---- conv2: 2 chunks of 4 images (grid (3,46)) ----
    for (int ch = 0; ch < 2; ++ch) {
        int b0 = ch * 4, nb = 4;
        int total = nb * 729 * 1600;
        im2col2_f16<<<(total + 255) / 256, 256, 0, stream>>>(pool1, col_h, col2_l, b0, nb);
        dim3 grid(3, (nb * 729 + 63) / 64);
        gemm_f16x3<64, 64, 2><<<grid, 256, 0, stream>>>(
            col_h, col2_l, 1600, wt2_h, wt2_l, 1600,
            conv2o + (size_t)b0 * 729 * 192, 192, nb * 729, 192, 1600,
            c2b, nullptr, nullptr, nullptr, nullptr);
    }
    maxpool3s2_nhwc<<<(BATCH * 13 * 13 * 192 + 255) / 256, 256, 0, stream>>>(
        conv2o, pool2, BATCH, 192, 27, 27, 13, 13);

    // ---- conv3 (grid (6,22)) ----
    {
        int total = 8 * 169 * 1728;
        im2col3_f16<<<(total + 255) / 256, 256, 0, stream>>>(pool2, col_h, col3_l);
        dim3 grid(6, (8 * 169 + 63) / 64);
        gemm_f16x3<64, 64, 0><<<grid, 256, 0, stream>>>(
            col_h, col3_l, 1728, wt3_h, wt3_l, 1728,
            featN, 384, 8 * 169, 384, 1728,
            c3b, nullptr, nullptr, nullptr, nullptr);
    }

    // ---- ROI pool + zero pad row ----
    roi_pool_kernel<<<(NROI * C_FEAT + 255) / 256, 256, 0, stream>>>(featN, bboxes, own, NROI, C_FEAT, 13, 13);
    zero_kernel<<<(N_VIS + 255) / 256, 256, 0, stream>>>(own + (size_t)NROI * N_VIS, N_VIS);

    // ---- encoder (64x64 tiles: grid (5,17)) ----
    f16* own_h  = (f16*)(S + 0);
    f16* own_l  = (f16*)(S + 1771200);
    f16* encB_h = (f16*)(S + 3542400);
    f16* encB_l = (f16*)(S + 4060800);     // ends 4,579,200 (spills into dead hbuf: ok)
    split_rowmajor<<<((NROI + 1) * N_VIS + 255) / 256, 256, 0, stream>>>(
        own, own_h, own_l, NROI + 1, N_VIS, N_VIS);
    {
        dim3 tg((N_VIS + 31) / 32, (HID + 31) / 32);
        transpose_split<<<tg, 256, 0, stream>>>(enc_w1, N_VIS, HID, 0, HID, N_VIS, encB_h, encB_l);
    }
    {
        dim3 grid((HID + 63) / 64, (NROI + 1 + 63) / 64);
        gemm_f16x3<64, 64, 1><<<grid, 256, 0, stream>>>(
            own_h, own_l, N_VIS, encB_h, encB_l, N_VIS,
            mid, HID, NROI + 1, HID, N_VIS,
            enc_b1, enc_g, enc_be, enc_m, enc_v);
    }
    {
        dim3 grid((HID + 63) / 64, (NROI + 1 + BM - 1) / BM);
        gemm_fp32_64<<<grid, 256, 0, stream>>>(mid, enc_w2, enc_all, NROI + 1, HID, HID, enc_b2);
    }

    // ---- attention + combined ----
    proj_kernel<<<NROI + 1, 128, 0, stream>>>(enc_all, att_w, s_own, proj_hi, NROI + 1, HID, NROI);
    att_combine_kernel<<<NROI, 512, 0, stream>>>(enc_all, ci, s_own, proj_hi, att_b,
                                                 own, bboxes, combined, NROI, HID);

    // ---- decoder layer 1: split combined (into dead own+featN region) ----
    f16* comb_h = (f16*)own;
    f16* comb_l = (f16*)(own + 1933312);
    split_rowmajor<<<(NROI * KPAD_DEC + 255) / 256, 256, 0, stream>>>(
        combined, comb_h, comb_l, NROI, NTOT, KPAD_DEC);

    if (full_dec) {
        // full Bt split of dec_w1, one big GEMM dispatch (grid (30,8) = 240 blocks)
        f16* Btd_h = (f16*)Btd_h_f;
        f16* Btd_l = (f16*)Btd_l_f;
        dim3 tg(KPAD_DEC / 32, KPAD_DEC / 32);
        transpose_split<<<tg, 256, 0, stream>>>(dec_w1, NTOT, NTOT, 0, KPAD_DEC, KPAD_DEC, Btd_h, Btd_l);
        dim3 grid((NTOT + 127) / 128, NROI / 128);   // FIX: was KPAD_DEC/128 = 29 (truncation) -> missing cols
        gemm_f16x3<128, 128, 1><<<grid, 256, 0, stream>>>(
            comb_h, comb_l, KPAD_DEC, Btd_h, Btd_l, KPAD_DEC,
            hbuf, NTOT, NROI, NTOT, KPAD_DEC,
            dec_b1, dec_g, dec_be, dec_m, dec_v);
    } else {
        // fallback: 4 N-chunks of 940, Btc inside dead `combined` region, 64x64 tiles
        f16* Btc_h = (f16*)(S + 0);
        f16* Btc_l = (f16*)(S + 1774720);  // ends 3,549,440 <= combined 3,850,240
        for (int c = 0; c < 4; ++c) {
            int nc0 = c * 940, NC = 940;
            dim3 tg(KPAD_DEC / 32, (NC + 31) / 32);
            transpose_split<<<tg, 256, 0, stream>>>(dec_w1, NTOT, NTOT, nc0, NC, KPAD_DEC, Btc_h, Btc_l);
            dim3 grid((NC + 63) / 64, NROI / 64);
            gemm_f16x3<64, 64, 1><<<grid, 256, 0, stream>>>(
                comb_h, comb_l, KPAD_DEC, Btc_h, Btc_l, KPAD_DEC,
                hbuf + nc0, NTOT, NROI, NC, KPAD_DEC,
                dec_b1 + nc0, dec_g + nc0, dec_be + nc0, dec_m + nc0, dec_v + nc0);
        }
    }

    gemv4_kernel<<<NROI, 256, 0, stream>>>(hbuf, dec_w2, dec_b2, out, NTOT);
}